// Round 5
// baseline (1285.032 us; speedup 1.0000x reference)
//
#include <hip/hip_runtime.h>

#define F 32

// ---- tile_scatter params ----
#define TILE 1024      // dst nodes per block
#define ROWP 33        // padded LDS row stride (floats) -> bank-conflict-free atomics
#define QCAP 2048      // LDS edge queue capacity
#define QTHRESH 512    // drain threshold
#define SBT 512        // threads per scatter block

// ---- hist params ----
#define SPAN 16384     // nodes per histogram range (64KB LDS)
#define HBT 256
#define BPG 16         // blocks per range

// out_deg histogram via LDS, coalesced flush. Replaces 1.6M random global atomics.
__global__ __launch_bounds__(HBT) void hist_kernel(const int* __restrict__ src,
                                                   int* __restrict__ out_deg,
                                                   int E, int N) {
    __shared__ int hist[SPAN];
    int grp = blockIdx.x / BPG;
    int q   = blockIdx.x % BPG;
    int lo  = grp * SPAN;
    int sp  = min(SPAN, N - lo);
    if (sp <= 0) return;  // uniform per block
    for (int j = threadIdx.x; j < SPAN; j += HBT) hist[j] = 0;
    __syncthreads();
    int nvec = E >> 2;
    const int4* s4 = (const int4*)src;
    for (int i = q * HBT + threadIdx.x; i < nvec; i += BPG * HBT) {
        int4 v = s4[i];
        unsigned a;
        a = (unsigned)(v.x - lo); if (a < (unsigned)sp) atomicAdd(&hist[a], 1);
        a = (unsigned)(v.y - lo); if (a < (unsigned)sp) atomicAdd(&hist[a], 1);
        a = (unsigned)(v.z - lo); if (a < (unsigned)sp) atomicAdd(&hist[a], 1);
        a = (unsigned)(v.w - lo); if (a < (unsigned)sp) atomicAdd(&hist[a], 1);
    }
    if (q == 0) {
        int idx = (nvec << 2) + threadIdx.x;
        if (idx < E) {
            unsigned a = (unsigned)(src[idx] - lo);
            if (a < (unsigned)sp) atomicAdd(&hist[a], 1);
        }
    }
    __syncthreads();
    for (int j = threadIdx.x; j < sp; j += HBT) {
        int v = hist[j];
        if (v) atomicAdd(&out_deg[lo + j], v);  // contiguous -> coalesced atomics
    }
}

// h = x * rsqrt(max(out_deg,1)) (dense). 8 lanes/node, float4/lane.
__global__ void prescale_kernel(const float* __restrict__ x, const int* __restrict__ out_deg,
                                float* __restrict__ h, int N) {
    int t = blockIdx.x * blockDim.x + threadIdx.x;
    int g = t >> 3, l = t & 7;
    if (g >= N) return;
    int d = out_deg[g];
    float c = rsqrtf((float)(d > 1 ? d : 1));
    float4 v = *reinterpret_cast<const float4*>(&x[(size_t)g * F + l * 4]);
    v.x *= c; v.y *= c; v.z *= c; v.w *= c;
    *reinterpret_cast<float4*>(&h[(size_t)g * F + l * 4]) = v;
}

// Each block owns a TILE-node dst range with an fp32 LDS accumulator.
// Scans the full edge list; matching edges go to an LDS queue, drained
// cooperatively (8 lanes/edge). In-degree counted in LDS. out written once.
// Zero per-edge global writes or atomics.
__global__ __launch_bounds__(SBT) void tile_scatter(const float* __restrict__ h,
                                                    const int* __restrict__ src,
                                                    const int* __restrict__ dst,
                                                    float* __restrict__ out,
                                                    int N, int E) {
    __shared__ float acc[TILE * ROWP];  // 132KB
    __shared__ int   cnt[TILE];         // 4KB
    __shared__ int   qbuf[QCAP];        // 8KB (packed: dl<<22 | s)
    __shared__ int   qcnt;
    const int tid = threadIdx.x;
    const int lo  = blockIdx.x * TILE;
    const int sp  = min(TILE, N - lo);

    for (int j = tid; j < TILE * ROWP; j += SBT) acc[j] = 0.f;
    for (int j = tid; j < TILE; j += SBT) cnt[j] = 0;
    if (tid == 0) qcnt = 0;
    __syncthreads();

    // Inline fallback if queue overflows (astronomically rare on random data).
    auto edge_add_inline = [&](unsigned dl, unsigned s) {
        float* row = &acc[dl * ROWP];
        const float4* hp = (const float4*)&h[(size_t)s * F];
        #pragma unroll
        for (int l = 0; l < 8; ++l) {
            float4 v = hp[l];
            atomicAdd(&row[l * 4 + 0], v.x);
            atomicAdd(&row[l * 4 + 1], v.y);
            atomicAdd(&row[l * 4 + 2], v.z);
            atomicAdd(&row[l * 4 + 3], v.w);
        }
        atomicAdd(&cnt[dl], 1);
    };
    auto push = [&](unsigned dl, int edge_idx) {
        unsigned s = (unsigned)src[edge_idx];
        int slot = atomicAdd(&qcnt, 1);
        if (slot < QCAP) qbuf[slot] = (int)((dl << 22) | s);
        else edge_add_inline(dl, s);
    };
    auto drain = [&](int n) {
        int l = tid & 7;
        for (int e = tid >> 3; e < n; e += SBT / 8) {
            unsigned pk = (unsigned)qbuf[e];
            unsigned s  = pk & 0x3FFFFFu;
            unsigned dl = pk >> 22;
            float4 v = *(const float4*)&h[(size_t)s * F + l * 4];
            float* row = &acc[dl * ROWP + l * 4];
            atomicAdd(&row[0], v.x);
            atomicAdd(&row[1], v.y);
            atomicAdd(&row[2], v.z);
            atomicAdd(&row[3], v.w);
            if (l == 0) atomicAdd(&cnt[dl], 1);
        }
    };

    const int4* d4 = (const int4*)dst;
    const int nvec = E >> 2;
    const int nwin = (nvec + SBT * 8 - 1) / (SBT * 8);
    int i = tid;
    for (int w = 0; w < nwin; ++w) {
        #pragma unroll
        for (int k = 0; k < 8; ++k, i += SBT) {
            if (i < nvec) {
                int4 v = d4[i];
                int e0 = i << 2;
                unsigned a;
                a = (unsigned)(v.x - lo); if (a < (unsigned)sp) push(a, e0 + 0);
                a = (unsigned)(v.y - lo); if (a < (unsigned)sp) push(a, e0 + 1);
                a = (unsigned)(v.z - lo); if (a < (unsigned)sp) push(a, e0 + 2);
                a = (unsigned)(v.w - lo); if (a < (unsigned)sp) push(a, e0 + 3);
            }
        }
        __syncthreads();  // appends of this window visible
        int n = qcnt; if (n > QCAP) n = QCAP;
        if (n >= QTHRESH) {
            drain(n);
            __syncthreads();              // drain done
            if (tid == 0) qcnt = 0;
            __syncthreads();              // reset visible before new appends
        }
    }
    // scalar tail (E % 4)
    int idx = (nvec << 2) + tid;
    if (idx < E) {
        unsigned a = (unsigned)(dst[idx] - lo);
        if (a < (unsigned)sp) push(a, idx);
    }
    __syncthreads();
    int n = qcnt; if (n > QCAP) n = QCAP;
    if (n > 0) drain(n);
    __syncthreads();

    // writeback: out[g] = acc[g] * rsqrt(max(in_deg,1)); coalesced float4.
    for (int j = tid; j < sp * 8; j += SBT) {
        int g = j >> 3, l = j & 7;
        int c = cnt[g];
        float inn = rsqrtf((float)(c > 1 ? c : 1));
        const float* ar = &acc[g * ROWP + l * 4];
        float4 o;
        o.x = ar[0] * inn; o.y = ar[1] * inn; o.z = ar[2] * inn; o.w = ar[3] * inn;
        *reinterpret_cast<float4*>(&out[(size_t)(lo + g) * F + l * 4]) = o;
    }
}

// ================= R3 fallback path (ws too small / N too large) =================

__global__ void deg_kernel(const int* __restrict__ src, const int* __restrict__ dst,
                           int* __restrict__ out_deg, int* __restrict__ in_deg, int E) {
    int i = blockIdx.x * blockDim.x + threadIdx.x;
    if (i < E) {
        atomicAdd(&out_deg[src[i]], 1);
        atomicAdd(&in_deg[dst[i]], 1);
    }
}

__global__ void norm_kernel(const int* __restrict__ deg, float* __restrict__ norm, int n) {
    int i = blockIdx.x * blockDim.x + threadIdx.x;
    if (i < n) {
        int d = deg[i];
        norm[i] = rsqrtf((float)(d > 1 ? d : 1));
    }
}

__global__ void alloc_kernel(const int* __restrict__ in_deg, int* __restrict__ cursor,
                             int* __restrict__ counter, int N) {
    int i = blockIdx.x * blockDim.x + threadIdx.x;
    if (i < N) cursor[i] = atomicAdd(counter, in_deg[i]);
}

__global__ void fill_kernel(const int* __restrict__ src, const int* __restrict__ dst,
                            int* __restrict__ cursor, int* __restrict__ edge_src, int E) {
    int i = blockIdx.x * blockDim.x + threadIdx.x;
    if (i < E) {
        int d = dst[i];
        int slot = atomicAdd(&cursor[d], 1);
        edge_src[slot] = src[i];
    }
}

__global__ void gather_kernel(const float* __restrict__ x,
                              const int* __restrict__ edge_src,
                              const int* __restrict__ cursor_end,
                              const int* __restrict__ in_deg,
                              const float* __restrict__ out_norm,
                              float* __restrict__ out, int N) {
    int t = blockIdx.x * blockDim.x + threadIdx.x;
    int g = t >> 3, l = t & 7;
    if (g >= N) return;
    int deg = in_deg[g];
    int end = cursor_end[g];
    int beg = end - deg;
    float4 acc = make_float4(0.f, 0.f, 0.f, 0.f);
    for (int j = beg; j < end; ++j) {
        int s = edge_src[j];
        float c = out_norm[s];
        float4 v = *reinterpret_cast<const float4*>(&x[s * F + l * 4]);
        acc.x += v.x * c; acc.y += v.y * c; acc.z += v.z * c; acc.w += v.w * c;
    }
    float innorm = rsqrtf((float)(deg > 1 ? deg : 1));
    acc.x *= innorm; acc.y *= innorm; acc.z *= innorm; acc.w *= innorm;
    *reinterpret_cast<float4*>(&out[g * F + l * 4]) = acc;
}

extern "C" void kernel_launch(void* const* d_in, const int* in_sizes, int n_in,
                              void* d_out, int out_size, void* d_ws, size_t ws_size,
                              hipStream_t stream) {
    const float* x  = (const float*)d_in[0];
    const int* src  = (const int*)d_in[1];
    const int* dst  = (const int*)d_in[2];
    float* out      = (float*)d_out;

    const int N = in_sizes[0] / F;   // 100000
    const int E = in_sizes[1];       // 1600000

    // primary ws layout: out_deg[N] ints | h[N*F] floats
    size_t need5 = ((size_t)N + (size_t)N * F) * 4;

    if (ws_size >= need5 && N < (1 << 22)) {
        int* out_deg = (int*)d_ws;
        float* h     = (float*)(out_deg + N);

        hipMemsetAsync(out_deg, 0, (size_t)N * sizeof(int), stream);

        int G = (N + SPAN - 1) / SPAN;
        hist_kernel<<<G * BPG, HBT, 0, stream>>>(src, out_deg, E, N);
        prescale_kernel<<<(N * 8 + 255) / 256, 256, 0, stream>>>(x, out_deg, h, N);
        int NB = (N + TILE - 1) / TILE;
        tile_scatter<<<NB, SBT, 0, stream>>>(h, src, dst, out, N, E);
        return;
    }

    // ---- R3 fallback ----
    size_t need3 = ((size_t)3 * N + 1 + (size_t)E) * sizeof(int);
    int* out_deg = (int*)d_ws;
    int* in_deg  = out_deg + N;
    if (ws_size >= need3) {
        int* counter  = in_deg + N;
        int* cursor   = counter + 1;
        int* edge_src = cursor + N;
        hipMemsetAsync(d_ws, 0, ((size_t)2 * N + 1) * sizeof(int), stream);
        deg_kernel<<<(E + 255) / 256, 256, 0, stream>>>(src, dst, out_deg, in_deg, E);
        norm_kernel<<<(N + 255) / 256, 256, 0, stream>>>(out_deg, (float*)out_deg, N);
        alloc_kernel<<<(N + 255) / 256, 256, 0, stream>>>(in_deg, cursor, counter, N);
        fill_kernel<<<(E + 255) / 256, 256, 0, stream>>>(src, dst, cursor, edge_src, E);
        gather_kernel<<<(N * 8 + 255) / 256, 256, 0, stream>>>(
            x, edge_src, cursor, in_deg, (const float*)out_deg, out, N);
    }
}

// Round 6
// 485.239 us; speedup vs baseline: 2.6482x; 2.6482x over previous
//
#include <hip/hip_runtime.h>

#define F 32

// ---- bucket params ----
#define TSB 128        // nodes per bucket (phase-2 tile)
#define TSB_SH 7
#define NBMAX 1024     // cnt/scan arrays padded to this
#define RND 4096       // edges per bin round (one block each)
#define BINT 256       // bin_kernel threads
#define GT 256         // bucket_gather threads

// ---- hist params (proven in R5) ----
#define SPAN 16384
#define HBT 256
#define BPG 16

// LDS histogram of `keys` into deg[], coalesced flush.
__global__ __launch_bounds__(HBT) void hist_kernel(const int* __restrict__ keys,
                                                   int* __restrict__ deg,
                                                   int E, int N) {
    __shared__ int hist[SPAN];
    int grp = blockIdx.x / BPG;
    int q   = blockIdx.x % BPG;
    int lo  = grp * SPAN;
    int sp  = min(SPAN, N - lo);
    if (sp <= 0) return;
    for (int j = threadIdx.x; j < SPAN; j += HBT) hist[j] = 0;
    __syncthreads();
    int nvec = E >> 2;
    const int4* s4 = (const int4*)keys;
    for (int i = q * HBT + threadIdx.x; i < nvec; i += BPG * HBT) {
        int4 v = s4[i];
        unsigned a;
        a = (unsigned)(v.x - lo); if (a < (unsigned)sp) atomicAdd(&hist[a], 1);
        a = (unsigned)(v.y - lo); if (a < (unsigned)sp) atomicAdd(&hist[a], 1);
        a = (unsigned)(v.z - lo); if (a < (unsigned)sp) atomicAdd(&hist[a], 1);
        a = (unsigned)(v.w - lo); if (a < (unsigned)sp) atomicAdd(&hist[a], 1);
    }
    if (q == 0) {
        int idx = (nvec << 2) + threadIdx.x;
        if (idx < E) {
            unsigned a = (unsigned)(keys[idx] - lo);
            if (a < (unsigned)sp) atomicAdd(&hist[a], 1);
        }
    }
    __syncthreads();
    for (int j = threadIdx.x; j < sp; j += HBT) {
        int v = hist[j];
        if (v) atomicAdd(&deg[lo + j], v);
    }
}

// Per-bucket exact region allocation: bases[b] = atomicAdd(counter, bucket_cnt).
// Order-free disjoint layout (R3 trick). gcur starts at bases.
__global__ void bucket_alloc(const int* __restrict__ in_deg, int* __restrict__ gcur,
                             int* __restrict__ bases, int* __restrict__ counter, int N) {
    __shared__ int ws[2];
    int b = blockIdx.x;
    int lo = b << TSB_SH;
    int t = threadIdx.x;  // 128
    int v = (lo + t < N) ? in_deg[lo + t] : 0;
    for (int off = 32; off; off >>= 1) v += __shfl_down(v, off, 64);
    if ((t & 63) == 0) ws[t >> 6] = v;
    __syncthreads();
    if (t == 0) {
        int c = ws[0] + ws[1];
        int base = atomicAdd(counter, c);
        bases[b] = base;
        gcur[b]  = base;
    }
}

// h = x * rsqrt(max(out_deg,1)); 8 lanes/node, float4/lane.
__global__ void prescale_kernel(const float* __restrict__ x, const int* __restrict__ out_deg,
                                float* __restrict__ h, int N) {
    int t = blockIdx.x * blockDim.x + threadIdx.x;
    int g = t >> 3, l = t & 7;
    if (g >= N) return;
    int d = out_deg[g];
    float c = rsqrtf((float)(d > 1 ? d : 1));
    float4 v = *reinterpret_cast<const float4*>(&x[(size_t)g * F + l * 4]);
    v.x *= c; v.y *= c; v.z *= c; v.w *= c;
    *reinterpret_cast<float4*>(&h[(size_t)g * F + l * 4]) = v;
}

// Bin 4096 edges/block into NB buckets: LDS count -> scan -> LDS-staged
// compaction -> one global atomic per (block,bucket) -> coalesced copy-out of
// packed entries (dst_local<<17 | src). Kills the 16x random-store write amp.
__global__ __launch_bounds__(BINT) void bin_kernel(const int* __restrict__ src,
                                                   const int* __restrict__ dst,
                                                   int* __restrict__ gcur,
                                                   unsigned* __restrict__ gbuf, int E) {
    __shared__ int cnt[NBMAX];
    __shared__ int off2[NBMAX];
    __shared__ int aux[BINT];
    __shared__ int stag_d[RND];
    __shared__ int stag_s[RND];
    int t = threadIdx.x;
    int base = blockIdx.x * RND;
    int tot = min(RND, E - base);
    if (tot <= 0) return;
    for (int j = t; j < NBMAX; j += BINT) cnt[j] = 0;
    __syncthreads();
    // pass A: count buckets
    for (int j = t; j < tot; j += BINT)
        atomicAdd(&cnt[dst[base + j] >> TSB_SH], 1);
    __syncthreads();
    // exclusive scan of cnt[1024] with 256 threads
    int c0 = cnt[4*t], c1 = cnt[4*t+1], c2 = cnt[4*t+2], c3 = cnt[4*t+3];
    aux[t] = c0 + c1 + c2 + c3;
    __syncthreads();
    for (int o = 1; o < BINT; o <<= 1) {
        int v = (t >= o) ? aux[t - o] : 0;
        __syncthreads();
        aux[t] += v;
        __syncthreads();
    }
    int eb = t ? aux[t - 1] : 0;
    cnt[4*t]   = eb;            off2[4*t]   = eb;
    cnt[4*t+1] = eb + c0;       off2[4*t+1] = eb + c0;
    cnt[4*t+2] = eb + c0 + c1;  off2[4*t+2] = eb + c0 + c1;
    cnt[4*t+3] = eb + c0 + c1 + c2; off2[4*t+3] = eb + c0 + c1 + c2;
    __syncthreads();
    // pass B: place into staging (cnt now = running cursor from off)
    for (int j = t; j < tot; j += BINT) {
        int d = dst[base + j];
        int s = src[base + j];
        int pos = atomicAdd(&cnt[d >> TSB_SH], 1);
        stag_d[pos] = d;
        stag_s[pos] = s;
    }
    __syncthreads();
    // per-bucket global alloc; off2 becomes (gbase - local_off) delta
    for (int b = t; b < NBMAX; b += BINT) {
        int c = cnt[b] - off2[b];
        if (c > 0) {
            int g = atomicAdd(&gcur[b], c);
            off2[b] = g - off2[b];
        }
    }
    __syncthreads();
    // copy-out: consecutive i within a bucket chunk -> consecutive global addrs
    for (int i = t; i < tot; i += BINT) {
        int d = stag_d[i];
        unsigned entry = ((unsigned)(d & (TSB - 1)) << 17) | (unsigned)stag_s[i];
        gbuf[off2[d >> TSB_SH] + i] = entry;
    }
}

// Phase 2: block b accumulates its 128-node tile in LDS from its own bucket's
// edges only. 8 lanes/edge, 128B coalesced h reads, LDS f32 atomics, out once.
__global__ __launch_bounds__(GT) void bucket_gather(const float* __restrict__ h,
                                                    const unsigned* __restrict__ gbuf,
                                                    const int* __restrict__ bases,
                                                    const int* __restrict__ in_deg,
                                                    float* __restrict__ out, int N) {
    __shared__ float acc[TSB * 33];
    __shared__ int cb_s;
    int t = threadIdx.x;
    int b = blockIdx.x;
    int lo = b << TSB_SH;
    int sp = min(TSB, N - lo);
    for (int j = t; j < TSB * 33; j += GT) acc[j] = 0.f;
    if (t == 0) cb_s = 0;
    __syncthreads();
    if (t < sp) atomicAdd(&cb_s, in_deg[lo + t]);
    __syncthreads();
    int cb = cb_s;
    int start = bases[b];
    int end = start + cb;
    int l = t & 7;
    int i = start + (t >> 3);
    const int step = GT / 8;  // 32
    // 2-way unroll for MLP
    for (; i + step < end; i += 2 * step) {
        unsigned e0 = gbuf[i];
        unsigned e1 = gbuf[i + step];
        unsigned s0 = e0 & 0x1FFFFu, d0 = e0 >> 17;
        unsigned s1 = e1 & 0x1FFFFu, d1 = e1 >> 17;
        float4 v0 = *(const float4*)&h[(size_t)s0 * F + l * 4];
        float4 v1 = *(const float4*)&h[(size_t)s1 * F + l * 4];
        float* r0 = &acc[d0 * 33 + l * 4];
        atomicAdd(&r0[0], v0.x); atomicAdd(&r0[1], v0.y);
        atomicAdd(&r0[2], v0.z); atomicAdd(&r0[3], v0.w);
        float* r1 = &acc[d1 * 33 + l * 4];
        atomicAdd(&r1[0], v1.x); atomicAdd(&r1[1], v1.y);
        atomicAdd(&r1[2], v1.z); atomicAdd(&r1[3], v1.w);
    }
    if (i < end) {
        unsigned e0 = gbuf[i];
        unsigned s0 = e0 & 0x1FFFFu, d0 = e0 >> 17;
        float4 v0 = *(const float4*)&h[(size_t)s0 * F + l * 4];
        float* r0 = &acc[d0 * 33 + l * 4];
        atomicAdd(&r0[0], v0.x); atomicAdd(&r0[1], v0.y);
        atomicAdd(&r0[2], v0.z); atomicAdd(&r0[3], v0.w);
    }
    __syncthreads();
    for (int j = t; j < sp * 8; j += GT) {
        int g = j >> 3, ll = j & 7;
        int dg = in_deg[lo + g];
        float inn = rsqrtf((float)(dg > 1 ? dg : 1));
        const float* ar = &acc[g * 33 + ll * 4];
        float4 o;
        o.x = ar[0] * inn; o.y = ar[1] * inn; o.z = ar[2] * inn; o.w = ar[3] * inn;
        *reinterpret_cast<float4*>(&out[(size_t)(lo + g) * F + ll * 4]) = o;
    }
}

// ================= R3 fallback path =================

__global__ void deg_kernel(const int* __restrict__ src, const int* __restrict__ dst,
                           int* __restrict__ out_deg, int* __restrict__ in_deg, int E) {
    int i = blockIdx.x * blockDim.x + threadIdx.x;
    if (i < E) {
        atomicAdd(&out_deg[src[i]], 1);
        atomicAdd(&in_deg[dst[i]], 1);
    }
}

__global__ void norm_kernel(const int* __restrict__ deg, float* __restrict__ norm, int n) {
    int i = blockIdx.x * blockDim.x + threadIdx.x;
    if (i < n) {
        int d = deg[i];
        norm[i] = rsqrtf((float)(d > 1 ? d : 1));
    }
}

__global__ void alloc_kernel(const int* __restrict__ in_deg, int* __restrict__ cursor,
                             int* __restrict__ counter, int N) {
    int i = blockIdx.x * blockDim.x + threadIdx.x;
    if (i < N) cursor[i] = atomicAdd(counter, in_deg[i]);
}

__global__ void fill_kernel(const int* __restrict__ src, const int* __restrict__ dst,
                            int* __restrict__ cursor, int* __restrict__ edge_src, int E) {
    int i = blockIdx.x * blockDim.x + threadIdx.x;
    if (i < E) {
        int d = dst[i];
        int slot = atomicAdd(&cursor[d], 1);
        edge_src[slot] = src[i];
    }
}

__global__ void gather_kernel(const float* __restrict__ x,
                              const int* __restrict__ edge_src,
                              const int* __restrict__ cursor_end,
                              const int* __restrict__ in_deg,
                              const float* __restrict__ out_norm,
                              float* __restrict__ out, int N) {
    int t = blockIdx.x * blockDim.x + threadIdx.x;
    int g = t >> 3, l = t & 7;
    if (g >= N) return;
    int deg = in_deg[g];
    int end = cursor_end[g];
    int beg = end - deg;
    float4 acc = make_float4(0.f, 0.f, 0.f, 0.f);
    for (int j = beg; j < end; ++j) {
        int s = edge_src[j];
        float c = out_norm[s];
        float4 v = *reinterpret_cast<const float4*>(&x[s * F + l * 4]);
        acc.x += v.x * c; acc.y += v.y * c; acc.z += v.z * c; acc.w += v.w * c;
    }
    float innorm = rsqrtf((float)(deg > 1 ? deg : 1));
    acc.x *= innorm; acc.y *= innorm; acc.z *= innorm; acc.w *= innorm;
    *reinterpret_cast<float4*>(&out[g * F + l * 4]) = acc;
}

extern "C" void kernel_launch(void* const* d_in, const int* in_sizes, int n_in,
                              void* d_out, int out_size, void* d_ws, size_t ws_size,
                              hipStream_t stream) {
    const float* x  = (const float*)d_in[0];
    const int* src  = (const int*)d_in[1];
    const int* dst  = (const int*)d_in[2];
    float* out      = (float*)d_out;

    const int N = in_sizes[0] / F;   // 100000
    const int E = in_sizes[1];       // 1600000
    const int NB = (N + TSB - 1) / TSB;

    // primary ws layout (4B units):
    // out_deg[N] | in_deg[N] | counter[8] | gcur[NBMAX] | bases[NBMAX] | gbuf[E] | h[N*F]
    size_t need6 = ((size_t)2 * N + 8 + 2 * NBMAX + (size_t)E + (size_t)N * F) * 4;

    if (ws_size >= need6 && N <= (1 << 17) && NB <= NBMAX) {
        int* out_deg  = (int*)d_ws;
        int* in_deg   = out_deg + N;
        int* counter  = in_deg + N;
        int* gcur     = counter + 8;
        int* bases    = gcur + NBMAX;
        unsigned* gbuf = (unsigned*)(bases + NBMAX);
        float* h      = (float*)(gbuf + E);

        // zero out_deg, in_deg, counter (contiguous head)
        hipMemsetAsync(d_ws, 0, ((size_t)2 * N + 8) * sizeof(int), stream);

        int G = (N + SPAN - 1) / SPAN;
        hist_kernel<<<G * BPG, HBT, 0, stream>>>(src, out_deg, E, N);
        hist_kernel<<<G * BPG, HBT, 0, stream>>>(dst, in_deg, E, N);
        bucket_alloc<<<NB, TSB, 0, stream>>>(in_deg, gcur, bases, counter, N);
        prescale_kernel<<<(N * 8 + 255) / 256, 256, 0, stream>>>(x, out_deg, h, N);
        bin_kernel<<<(E + RND - 1) / RND, BINT, 0, stream>>>(src, dst, gcur, gbuf, E);
        bucket_gather<<<NB, GT, 0, stream>>>(h, gbuf, bases, in_deg, out, N);
        return;
    }

    // ---- R3 fallback ----
    size_t need3 = ((size_t)3 * N + 1 + (size_t)E) * sizeof(int);
    int* out_deg = (int*)d_ws;
    int* in_deg  = out_deg + N;
    if (ws_size >= need3) {
        int* counter  = in_deg + N;
        int* cursor   = counter + 1;
        int* edge_src = cursor + N;
        hipMemsetAsync(d_ws, 0, ((size_t)2 * N + 1) * sizeof(int), stream);
        deg_kernel<<<(E + 255) / 256, 256, 0, stream>>>(src, dst, out_deg, in_deg, E);
        norm_kernel<<<(N + 255) / 256, 256, 0, stream>>>(out_deg, (float*)out_deg, N);
        alloc_kernel<<<(N + 255) / 256, 256, 0, stream>>>(in_deg, cursor, counter, N);
        fill_kernel<<<(E + 255) / 256, 256, 0, stream>>>(src, dst, cursor, edge_src, E);
        gather_kernel<<<(N * 8 + 255) / 256, 256, 0, stream>>>(
            x, edge_src, cursor, in_deg, (const float*)out_deg, out, N);
    }
}

// Round 7
// 432.056 us; speedup vs baseline: 2.9742x; 1.1231x over previous
//
#include <hip/hip_runtime.h>

#define F 32

// ---- bucket params ----
#define TSB 128        // nodes per bucket
#define TSB_SH 7
#define NBMAX 1024     // bucket arrays padded to this (NB = ceil(N/128) <= 1024)
#define RND 4096       // edges per bin round (one block each)
#define BINT 256       // bin_kernel threads
#define GT 1024        // bucket_gather threads (16 waves -> 2 blocks/CU = 100% occ)

// ---- per-node src hist params ----
#define SPAN 16384
#define HBT 256
#define BPG 16

// LDS histogram of src into out_deg (per node), coalesced flush.
__global__ __launch_bounds__(HBT) void hist_kernel(const int* __restrict__ keys,
                                                   int* __restrict__ deg,
                                                   int E, int N) {
    __shared__ int hist[SPAN];
    int grp = blockIdx.x / BPG;
    int q   = blockIdx.x % BPG;
    int lo  = grp * SPAN;
    int sp  = min(SPAN, N - lo);
    if (sp <= 0) return;
    for (int j = threadIdx.x; j < SPAN; j += HBT) hist[j] = 0;
    __syncthreads();
    int nvec = E >> 2;
    const int4* s4 = (const int4*)keys;
    for (int i = q * HBT + threadIdx.x; i < nvec; i += BPG * HBT) {
        int4 v = s4[i];
        unsigned a;
        a = (unsigned)(v.x - lo); if (a < (unsigned)sp) atomicAdd(&hist[a], 1);
        a = (unsigned)(v.y - lo); if (a < (unsigned)sp) atomicAdd(&hist[a], 1);
        a = (unsigned)(v.z - lo); if (a < (unsigned)sp) atomicAdd(&hist[a], 1);
        a = (unsigned)(v.w - lo); if (a < (unsigned)sp) atomicAdd(&hist[a], 1);
    }
    if (q == 0) {
        int idx = (nvec << 2) + threadIdx.x;
        if (idx < E) {
            unsigned a = (unsigned)(keys[idx] - lo);
            if (a < (unsigned)sp) atomicAdd(&hist[a], 1);
        }
    }
    __syncthreads();
    for (int j = threadIdx.x; j < sp; j += HBT) {
        int v = hist[j];
        if (v) atomicAdd(&deg[lo + j], v);
    }
}

// deg -> rsqrt(max(deg,1)) in place.
__global__ void norm_kernel(const int* __restrict__ deg, float* __restrict__ norm, int n) {
    int i = blockIdx.x * blockDim.x + threadIdx.x;
    if (i < n) {
        int d = deg[i];
        norm[i] = rsqrtf((float)(d > 1 ? d : 1));
    }
}

// Bucket-level histogram: cntB[dst>>7]. One pass over dst (6.4MB), 1024-bin LDS.
__global__ __launch_bounds__(256) void bhist_kernel(const int* __restrict__ dst,
                                                    int* __restrict__ cntB, int E) {
    __shared__ int hist[NBMAX];
    int t = threadIdx.x;
    for (int j = t; j < NBMAX; j += 256) hist[j] = 0;
    __syncthreads();
    int nvec = E >> 2;
    const int4* d4 = (const int4*)dst;
    for (int i = blockIdx.x * 256 + t; i < nvec; i += gridDim.x * 256) {
        int4 v = d4[i];
        atomicAdd(&hist[v.x >> TSB_SH], 1);
        atomicAdd(&hist[v.y >> TSB_SH], 1);
        atomicAdd(&hist[v.z >> TSB_SH], 1);
        atomicAdd(&hist[v.w >> TSB_SH], 1);
    }
    if (blockIdx.x == 0) {
        int idx = (nvec << 2) + t;
        if (idx < E) atomicAdd(&hist[dst[idx] >> TSB_SH], 1);
    }
    __syncthreads();
    for (int j = t; j < NBMAX; j += 256) {
        int v = hist[j];
        if (v) atomicAdd(&cntB[j], v);
    }
}

// Disjoint region per bucket: bases[b]=gcur[b]=atomicAdd(counter,cntB[b]).
__global__ void bucket_alloc2(const int* __restrict__ cntB, int* __restrict__ gcur,
                              int* __restrict__ bases, int* __restrict__ counter, int NB) {
    int b = blockIdx.x * blockDim.x + threadIdx.x;
    if (b < NB) {
        int base = atomicAdd(counter, cntB[b]);
        bases[b] = base;
        gcur[b]  = base;
    }
}

// Bin 4096 edges/block into buckets: LDS count -> scan -> staged compaction ->
// one global atomic per (block,bucket) -> coalesced copy-out of packed entries.
__global__ __launch_bounds__(BINT) void bin_kernel(const int* __restrict__ src,
                                                   const int* __restrict__ dst,
                                                   int* __restrict__ gcur,
                                                   unsigned* __restrict__ gbuf, int E) {
    __shared__ int cnt[NBMAX];
    __shared__ int off2[NBMAX];
    __shared__ int aux[BINT];
    __shared__ int stag_d[RND];
    __shared__ int stag_s[RND];
    int t = threadIdx.x;
    int base = blockIdx.x * RND;
    int tot = min(RND, E - base);
    if (tot <= 0) return;
    for (int j = t; j < NBMAX; j += BINT) cnt[j] = 0;
    __syncthreads();
    for (int j = t; j < tot; j += BINT)
        atomicAdd(&cnt[dst[base + j] >> TSB_SH], 1);
    __syncthreads();
    int c0 = cnt[4*t], c1 = cnt[4*t+1], c2 = cnt[4*t+2], c3 = cnt[4*t+3];
    aux[t] = c0 + c1 + c2 + c3;
    __syncthreads();
    for (int o = 1; o < BINT; o <<= 1) {
        int v = (t >= o) ? aux[t - o] : 0;
        __syncthreads();
        aux[t] += v;
        __syncthreads();
    }
    int eb = t ? aux[t - 1] : 0;
    cnt[4*t]   = eb;                off2[4*t]   = eb;
    cnt[4*t+1] = eb + c0;           off2[4*t+1] = eb + c0;
    cnt[4*t+2] = eb + c0 + c1;      off2[4*t+2] = eb + c0 + c1;
    cnt[4*t+3] = eb + c0 + c1 + c2; off2[4*t+3] = eb + c0 + c1 + c2;
    __syncthreads();
    for (int j = t; j < tot; j += BINT) {
        int d = dst[base + j];
        int s = src[base + j];
        int pos = atomicAdd(&cnt[d >> TSB_SH], 1);
        stag_d[pos] = d;
        stag_s[pos] = s;
    }
    __syncthreads();
    for (int b = t; b < NBMAX; b += BINT) {
        int c = cnt[b] - off2[b];
        if (c > 0) {
            int g = atomicAdd(&gcur[b], c);
            off2[b] = g - off2[b];
        }
    }
    __syncthreads();
    for (int i = t; i < tot; i += BINT) {
        int d = stag_d[i];
        unsigned entry = ((unsigned)(d & (TSB - 1)) << 17) | (unsigned)stag_s[i];
        gbuf[off2[d >> TSB_SH] + i] = entry;
    }
}

// Phase 2: block b accumulates its 128-node tile in LDS from its bucket's edges.
// 16 waves/block (2 blocks/CU = full occupancy), unroll-4 for MLP. x*out_norm
// folded inline; in-degree counted in LDS. out written once, coalesced.
__global__ __launch_bounds__(GT) void bucket_gather2(const float* __restrict__ x,
                                                     const float* __restrict__ onorm,
                                                     const unsigned* __restrict__ gbuf,
                                                     const int* __restrict__ bases,
                                                     const int* __restrict__ cntB,
                                                     float* __restrict__ out, int N) {
    __shared__ float acc[TSB * 33];
    __shared__ int   cnt[TSB];
    int t = threadIdx.x;
    int b = blockIdx.x;
    int lo = b << TSB_SH;
    int sp = min(TSB, N - lo);
    for (int j = t; j < TSB * 33; j += GT) acc[j] = 0.f;
    for (int j = t; j < TSB; j += GT) cnt[j] = 0;
    __syncthreads();
    int start = bases[b];
    int end = start + cntB[b];
    int l = t & 7;
    const int step = GT / 8;  // 128 groups
    const float4* x4 = (const float4*)x;

    auto body = [&](unsigned e) {
        unsigned s  = e & 0x1FFFFu;
        unsigned dl = e >> 17;
        float c = onorm[s];
        float4 v = x4[(size_t)s * 8 + l];
        float* r = &acc[dl * 33 + l * 4];
        atomicAdd(&r[0], v.x * c);
        atomicAdd(&r[1], v.y * c);
        atomicAdd(&r[2], v.z * c);
        atomicAdd(&r[3], v.w * c);
        if (l == 0) atomicAdd(&cnt[dl], 1);
    };

    int i = start + (t >> 3);
    for (; i + 3 * step < end; i += 4 * step) {
        unsigned e0 = gbuf[i];
        unsigned e1 = gbuf[i + step];
        unsigned e2 = gbuf[i + 2 * step];
        unsigned e3 = gbuf[i + 3 * step];
        body(e0); body(e1); body(e2); body(e3);
    }
    for (; i < end; i += step) body(gbuf[i]);
    __syncthreads();

    for (int j = t; j < sp * 8; j += GT) {
        int g = j >> 3, ll = j & 7;
        int dg = cnt[g];
        float inn = rsqrtf((float)(dg > 1 ? dg : 1));
        const float* ar = &acc[g * 33 + ll * 4];
        float4 o;
        o.x = ar[0] * inn; o.y = ar[1] * inn; o.z = ar[2] * inn; o.w = ar[3] * inn;
        *reinterpret_cast<float4*>(&out[(size_t)(lo + g) * F + ll * 4]) = o;
    }
}

// ================= R3 fallback path =================

__global__ void deg_kernel(const int* __restrict__ src, const int* __restrict__ dst,
                           int* __restrict__ out_deg, int* __restrict__ in_deg, int E) {
    int i = blockIdx.x * blockDim.x + threadIdx.x;
    if (i < E) {
        atomicAdd(&out_deg[src[i]], 1);
        atomicAdd(&in_deg[dst[i]], 1);
    }
}

__global__ void alloc_kernel(const int* __restrict__ in_deg, int* __restrict__ cursor,
                             int* __restrict__ counter, int N) {
    int i = blockIdx.x * blockDim.x + threadIdx.x;
    if (i < N) cursor[i] = atomicAdd(counter, in_deg[i]);
}

__global__ void fill_kernel(const int* __restrict__ src, const int* __restrict__ dst,
                            int* __restrict__ cursor, int* __restrict__ edge_src, int E) {
    int i = blockIdx.x * blockDim.x + threadIdx.x;
    if (i < E) {
        int d = dst[i];
        int slot = atomicAdd(&cursor[d], 1);
        edge_src[slot] = src[i];
    }
}

__global__ void gather_kernel(const float* __restrict__ x,
                              const int* __restrict__ edge_src,
                              const int* __restrict__ cursor_end,
                              const int* __restrict__ in_deg,
                              const float* __restrict__ out_norm,
                              float* __restrict__ out, int N) {
    int t = blockIdx.x * blockDim.x + threadIdx.x;
    int g = t >> 3, l = t & 7;
    if (g >= N) return;
    int deg = in_deg[g];
    int end = cursor_end[g];
    int beg = end - deg;
    float4 acc = make_float4(0.f, 0.f, 0.f, 0.f);
    for (int j = beg; j < end; ++j) {
        int s = edge_src[j];
        float c = out_norm[s];
        float4 v = *reinterpret_cast<const float4*>(&x[s * F + l * 4]);
        acc.x += v.x * c; acc.y += v.y * c; acc.z += v.z * c; acc.w += v.w * c;
    }
    float innorm = rsqrtf((float)(deg > 1 ? deg : 1));
    acc.x *= innorm; acc.y *= innorm; acc.z *= innorm; acc.w *= innorm;
    *reinterpret_cast<float4*>(&out[g * F + l * 4]) = acc;
}

extern "C" void kernel_launch(void* const* d_in, const int* in_sizes, int n_in,
                              void* d_out, int out_size, void* d_ws, size_t ws_size,
                              hipStream_t stream) {
    const float* x  = (const float*)d_in[0];
    const int* src  = (const int*)d_in[1];
    const int* dst  = (const int*)d_in[2];
    float* out      = (float*)d_out;

    const int N = in_sizes[0] / F;   // 100000
    const int E = in_sizes[1];       // 1600000
    const int NB = (N + TSB - 1) / TSB;

    // primary ws layout (4B units):
    // out_deg[N] | counter[8] | cntB[NBMAX] | gcur[NBMAX] | bases[NBMAX] | gbuf[E]
    size_t need7 = ((size_t)N + 8 + 3 * NBMAX + (size_t)E) * 4;

    if (ws_size >= need7 && N <= (1 << 17) && NB <= NBMAX) {
        int* out_deg  = (int*)d_ws;
        int* counter  = out_deg + N;
        int* cntB     = counter + 8;
        int* gcur     = cntB + NBMAX;
        int* bases    = gcur + NBMAX;
        unsigned* gbuf = (unsigned*)(bases + NBMAX);

        // zero out_deg, counter, cntB (contiguous head)
        hipMemsetAsync(d_ws, 0, ((size_t)N + 8 + NBMAX) * sizeof(int), stream);

        int G = (N + SPAN - 1) / SPAN;
        hist_kernel<<<G * BPG, HBT, 0, stream>>>(src, out_deg, E, N);
        norm_kernel<<<(N + 255) / 256, 256, 0, stream>>>(out_deg, (float*)out_deg, N);
        bhist_kernel<<<256, 256, 0, stream>>>(dst, cntB, E);
        bucket_alloc2<<<(NB + 255) / 256, 256, 0, stream>>>(cntB, gcur, bases, counter, NB);
        bin_kernel<<<(E + RND - 1) / RND, BINT, 0, stream>>>(src, dst, gcur, gbuf, E);
        bucket_gather2<<<NB, GT, 0, stream>>>(x, (const float*)out_deg, gbuf, bases,
                                              cntB, out, N);
        return;
    }

    // ---- R3 fallback ----
    size_t need3 = ((size_t)3 * N + 1 + (size_t)E) * sizeof(int);
    int* out_deg = (int*)d_ws;
    int* in_deg  = out_deg + N;
    if (ws_size >= need3) {
        int* counter  = in_deg + N;
        int* cursor   = counter + 1;
        int* edge_src = cursor + N;
        hipMemsetAsync(d_ws, 0, ((size_t)2 * N + 1) * sizeof(int), stream);
        deg_kernel<<<(E + 255) / 256, 256, 0, stream>>>(src, dst, out_deg, in_deg, E);
        norm_kernel<<<(N + 255) / 256, 256, 0, stream>>>(out_deg, (float*)out_deg, N);
        alloc_kernel<<<(N + 255) / 256, 256, 0, stream>>>(in_deg, cursor, counter, N);
        fill_kernel<<<(E + 255) / 256, 256, 0, stream>>>(src, dst, cursor, edge_src, E);
        gather_kernel<<<(N * 8 + 255) / 256, 256, 0, stream>>>(
            x, edge_src, cursor, in_deg, (const float*)out_deg, out, N);
    }
}

// Round 8
// 133.429 us; speedup vs baseline: 9.6308x; 3.2381x over previous
//
#include <hip/hip_runtime.h>

#define F 32

// ---- bucket params ----
#define TSB 128        // nodes per bucket
#define TSB_SH 7
#define NBMAX 1024     // bucket arrays padded to this (NB = ceil(N/128) <= 1024)
#define RND 4096       // edges per bin round (one block each)
#define BINT 256       // bin_kernel threads
#define GT 1024        // sort_gather threads: 128 groups x 8 lanes
#define TEDGE 2048     // entries per in-block sort tile

// ---- per-node src hist params ----
#define SPAN 16384
#define HBT 256
#define BPG 16

// LDS histogram of src into out_deg (per node), coalesced flush.
__global__ __launch_bounds__(HBT) void hist_kernel(const int* __restrict__ keys,
                                                   int* __restrict__ deg,
                                                   int E, int N) {
    __shared__ int hist[SPAN];
    int grp = blockIdx.x / BPG;
    int q   = blockIdx.x % BPG;
    int lo  = grp * SPAN;
    int sp  = min(SPAN, N - lo);
    if (sp <= 0) return;
    for (int j = threadIdx.x; j < SPAN; j += HBT) hist[j] = 0;
    __syncthreads();
    int nvec = E >> 2;
    const int4* s4 = (const int4*)keys;
    for (int i = q * HBT + threadIdx.x; i < nvec; i += BPG * HBT) {
        int4 v = s4[i];
        unsigned a;
        a = (unsigned)(v.x - lo); if (a < (unsigned)sp) atomicAdd(&hist[a], 1);
        a = (unsigned)(v.y - lo); if (a < (unsigned)sp) atomicAdd(&hist[a], 1);
        a = (unsigned)(v.z - lo); if (a < (unsigned)sp) atomicAdd(&hist[a], 1);
        a = (unsigned)(v.w - lo); if (a < (unsigned)sp) atomicAdd(&hist[a], 1);
    }
    if (q == 0) {
        int idx = (nvec << 2) + threadIdx.x;
        if (idx < E) {
            unsigned a = (unsigned)(keys[idx] - lo);
            if (a < (unsigned)sp) atomicAdd(&hist[a], 1);
        }
    }
    __syncthreads();
    for (int j = threadIdx.x; j < sp; j += HBT) {
        int v = hist[j];
        if (v) atomicAdd(&deg[lo + j], v);
    }
}

// deg -> rsqrt(max(deg,1)) in place.
__global__ void norm_kernel(const int* __restrict__ deg, float* __restrict__ norm, int n) {
    int i = blockIdx.x * blockDim.x + threadIdx.x;
    if (i < n) {
        int d = deg[i];
        norm[i] = rsqrtf((float)(d > 1 ? d : 1));
    }
}

// Bucket-level histogram: cntB[dst>>7]. One pass over dst, 1024-bin LDS.
__global__ __launch_bounds__(256) void bhist_kernel(const int* __restrict__ dst,
                                                    int* __restrict__ cntB, int E) {
    __shared__ int hist[NBMAX];
    int t = threadIdx.x;
    for (int j = t; j < NBMAX; j += 256) hist[j] = 0;
    __syncthreads();
    int nvec = E >> 2;
    const int4* d4 = (const int4*)dst;
    for (int i = blockIdx.x * 256 + t; i < nvec; i += gridDim.x * 256) {
        int4 v = d4[i];
        atomicAdd(&hist[v.x >> TSB_SH], 1);
        atomicAdd(&hist[v.y >> TSB_SH], 1);
        atomicAdd(&hist[v.z >> TSB_SH], 1);
        atomicAdd(&hist[v.w >> TSB_SH], 1);
    }
    if (blockIdx.x == 0) {
        int idx = (nvec << 2) + t;
        if (idx < E) atomicAdd(&hist[dst[idx] >> TSB_SH], 1);
    }
    __syncthreads();
    for (int j = t; j < NBMAX; j += 256) {
        int v = hist[j];
        if (v) atomicAdd(&cntB[j], v);
    }
}

// Disjoint region per bucket: bases[b]=gcur[b]=atomicAdd(counter,cntB[b]).
__global__ void bucket_alloc2(const int* __restrict__ cntB, int* __restrict__ gcur,
                              int* __restrict__ bases, int* __restrict__ counter, int NB) {
    int b = blockIdx.x * blockDim.x + threadIdx.x;
    if (b < NB) {
        int base = atomicAdd(counter, cntB[b]);
        bases[b] = base;
        gcur[b]  = base;
    }
}

// Bin 4096 edges/block into buckets: LDS count -> scan -> staged compaction ->
// one global atomic per (block,bucket) -> coalesced copy-out of packed entries.
__global__ __launch_bounds__(BINT) void bin_kernel(const int* __restrict__ src,
                                                   const int* __restrict__ dst,
                                                   int* __restrict__ gcur,
                                                   unsigned* __restrict__ gbuf, int E) {
    __shared__ int cnt[NBMAX];
    __shared__ int off2[NBMAX];
    __shared__ int aux[BINT];
    __shared__ int stag_d[RND];
    __shared__ int stag_s[RND];
    int t = threadIdx.x;
    int base = blockIdx.x * RND;
    int tot = min(RND, E - base);
    if (tot <= 0) return;
    for (int j = t; j < NBMAX; j += BINT) cnt[j] = 0;
    __syncthreads();
    for (int j = t; j < tot; j += BINT)
        atomicAdd(&cnt[dst[base + j] >> TSB_SH], 1);
    __syncthreads();
    int c0 = cnt[4*t], c1 = cnt[4*t+1], c2 = cnt[4*t+2], c3 = cnt[4*t+3];
    aux[t] = c0 + c1 + c2 + c3;
    __syncthreads();
    for (int o = 1; o < BINT; o <<= 1) {
        int v = (t >= o) ? aux[t - o] : 0;
        __syncthreads();
        aux[t] += v;
        __syncthreads();
    }
    int eb = t ? aux[t - 1] : 0;
    cnt[4*t]   = eb;                off2[4*t]   = eb;
    cnt[4*t+1] = eb + c0;           off2[4*t+1] = eb + c0;
    cnt[4*t+2] = eb + c0 + c1;      off2[4*t+2] = eb + c0 + c1;
    cnt[4*t+3] = eb + c0 + c1 + c2; off2[4*t+3] = eb + c0 + c1 + c2;
    __syncthreads();
    for (int j = t; j < tot; j += BINT) {
        int d = dst[base + j];
        int s = src[base + j];
        int pos = atomicAdd(&cnt[d >> TSB_SH], 1);
        stag_d[pos] = d;
        stag_s[pos] = s;
    }
    __syncthreads();
    for (int b = t; b < NBMAX; b += BINT) {
        int c = cnt[b] - off2[b];
        if (c > 0) {
            int g = atomicAdd(&gcur[b], c);
            off2[b] = g - off2[b];
        }
    }
    __syncthreads();
    for (int i = t; i < tot; i += BINT) {
        int d = stag_d[i];
        unsigned entry = ((unsigned)(d & (TSB - 1)) << 17) | (unsigned)stag_s[i];
        gbuf[off2[d >> TSB_SH] + i] = entry;
    }
}

// Phase 2: per-bucket counting sort (int LDS atomics only) -> per-node REGISTER
// accumulation. Group g (8 lanes) owns node lo+g; walks its sorted segment,
// accumulating float4 in registers. No LDS float atomics. out written once.
__global__ __launch_bounds__(GT) void sort_gather(const float* __restrict__ x,
                                                  const float* __restrict__ onorm,
                                                  const unsigned* __restrict__ gbuf,
                                                  const int* __restrict__ bases,
                                                  const int* __restrict__ cntB,
                                                  float* __restrict__ out, int N) {
    __shared__ unsigned sbuf[TEDGE];  // sorted entries (8KB)
    __shared__ int cnt[TSB];          // count -> cursor
    __shared__ int seg[TSB];          // segment base
    __shared__ int sb[TSB];           // scan buffer
    __shared__ int indeg[TSB];        // in-degree accumulated over tiles
    int t = threadIdx.x;
    int b = blockIdx.x;
    int lo = b << TSB_SH;
    int sp = min(TSB, N - lo);
    int start = bases[b];
    int total = cntB[b];
    int g = t >> 3;     // 0..127 local node
    int l = t & 7;      // feature quad

    float4 acc = make_float4(0.f, 0.f, 0.f, 0.f);
    if (t < TSB) indeg[t] = 0;
    __syncthreads();

    for (int tile = 0; tile < total; tile += TEDGE) {
        int n = min(TEDGE, total - tile);
        if (t < TSB) cnt[t] = 0;
        __syncthreads();
        // count
        for (int j = t; j < n; j += GT)
            atomicAdd(&cnt[gbuf[start + tile + j] >> 17], 1);
        __syncthreads();
        int c_t = (t < TSB) ? cnt[t] : 0;
        if (t < TSB) sb[t] = c_t;
        __syncthreads();
        // inclusive Hillis-Steele scan over sb[0..127]
        for (int o = 1; o < TSB; o <<= 1) {
            int v = (t < TSB && t >= o) ? sb[t - o] : 0;
            __syncthreads();
            if (t < TSB) sb[t] += v;
            __syncthreads();
        }
        if (t < TSB) {
            int excl = sb[t] - c_t;
            seg[t] = excl;
            cnt[t] = excl;      // live cursor
            indeg[t] += c_t;
        }
        __syncthreads();
        // place (sort by dl)
        for (int j = t; j < n; j += GT) {
            unsigned e = gbuf[start + tile + j];
            int pos = atomicAdd(&cnt[e >> 17], 1);
            sbuf[pos] = e;
        }
        __syncthreads();
        // consume: group g's segment, register accumulation, unroll-2
        {
            int i = seg[g];
            int send = cnt[g];   // == seg[g] + count_g
            for (; i + 1 < send; i += 2) {
                unsigned e0 = sbuf[i], e1 = sbuf[i + 1];
                unsigned s0 = e0 & 0x1FFFFu, s1 = e1 & 0x1FFFFu;
                float c0 = onorm[s0];
                float c1 = onorm[s1];
                float4 v0 = *(const float4*)&x[(size_t)s0 * F + l * 4];
                float4 v1 = *(const float4*)&x[(size_t)s1 * F + l * 4];
                acc.x += v0.x * c0 + v1.x * c1;
                acc.y += v0.y * c0 + v1.y * c1;
                acc.z += v0.z * c0 + v1.z * c1;
                acc.w += v0.w * c0 + v1.w * c1;
            }
            if (i < send) {
                unsigned e0 = sbuf[i];
                unsigned s0 = e0 & 0x1FFFFu;
                float c0 = onorm[s0];
                float4 v0 = *(const float4*)&x[(size_t)s0 * F + l * 4];
                acc.x += v0.x * c0; acc.y += v0.y * c0;
                acc.z += v0.z * c0; acc.w += v0.w * c0;
            }
        }
        __syncthreads();  // protect cnt/sbuf before next tile
    }

    if (g < sp) {
        int dg = indeg[g];
        float inn = rsqrtf((float)(dg > 1 ? dg : 1));
        acc.x *= inn; acc.y *= inn; acc.z *= inn; acc.w *= inn;
        *reinterpret_cast<float4*>(&out[(size_t)(lo + g) * F + l * 4]) = acc;
    }
}

// ================= R3 fallback path =================

__global__ void deg_kernel(const int* __restrict__ src, const int* __restrict__ dst,
                           int* __restrict__ out_deg, int* __restrict__ in_deg, int E) {
    int i = blockIdx.x * blockDim.x + threadIdx.x;
    if (i < E) {
        atomicAdd(&out_deg[src[i]], 1);
        atomicAdd(&in_deg[dst[i]], 1);
    }
}

__global__ void alloc_kernel(const int* __restrict__ in_deg, int* __restrict__ cursor,
                             int* __restrict__ counter, int N) {
    int i = blockIdx.x * blockDim.x + threadIdx.x;
    if (i < N) cursor[i] = atomicAdd(counter, in_deg[i]);
}

__global__ void fill_kernel(const int* __restrict__ src, const int* __restrict__ dst,
                            int* __restrict__ cursor, int* __restrict__ edge_src, int E) {
    int i = blockIdx.x * blockDim.x + threadIdx.x;
    if (i < E) {
        int d = dst[i];
        int slot = atomicAdd(&cursor[d], 1);
        edge_src[slot] = src[i];
    }
}

__global__ void gather_kernel(const float* __restrict__ x,
                              const int* __restrict__ edge_src,
                              const int* __restrict__ cursor_end,
                              const int* __restrict__ in_deg,
                              const float* __restrict__ out_norm,
                              float* __restrict__ out, int N) {
    int t = blockIdx.x * blockDim.x + threadIdx.x;
    int g = t >> 3, l = t & 7;
    if (g >= N) return;
    int deg = in_deg[g];
    int end = cursor_end[g];
    int beg = end - deg;
    float4 acc = make_float4(0.f, 0.f, 0.f, 0.f);
    for (int j = beg; j < end; ++j) {
        int s = edge_src[j];
        float c = out_norm[s];
        float4 v = *reinterpret_cast<const float4*>(&x[s * F + l * 4]);
        acc.x += v.x * c; acc.y += v.y * c; acc.z += v.z * c; acc.w += v.w * c;
    }
    float innorm = rsqrtf((float)(deg > 1 ? deg : 1));
    acc.x *= innorm; acc.y *= innorm; acc.z *= innorm; acc.w *= innorm;
    *reinterpret_cast<float4*>(&out[g * F + l * 4]) = acc;
}

extern "C" void kernel_launch(void* const* d_in, const int* in_sizes, int n_in,
                              void* d_out, int out_size, void* d_ws, size_t ws_size,
                              hipStream_t stream) {
    const float* x  = (const float*)d_in[0];
    const int* src  = (const int*)d_in[1];
    const int* dst  = (const int*)d_in[2];
    float* out      = (float*)d_out;

    const int N = in_sizes[0] / F;   // 100000
    const int E = in_sizes[1];       // 1600000
    const int NB = (N + TSB - 1) / TSB;

    // primary ws layout (4B units):
    // out_deg[N] | counter[8] | cntB[NBMAX] | gcur[NBMAX] | bases[NBMAX] | gbuf[E]
    size_t need = ((size_t)N + 8 + 3 * NBMAX + (size_t)E) * 4;

    if (ws_size >= need && N <= (1 << 17) && NB <= NBMAX) {
        int* out_deg  = (int*)d_ws;
        int* counter  = out_deg + N;
        int* cntB     = counter + 8;
        int* gcur     = cntB + NBMAX;
        int* bases    = gcur + NBMAX;
        unsigned* gbuf = (unsigned*)(bases + NBMAX);

        // zero out_deg, counter, cntB (contiguous head)
        hipMemsetAsync(d_ws, 0, ((size_t)N + 8 + NBMAX) * sizeof(int), stream);

        int G = (N + SPAN - 1) / SPAN;
        hist_kernel<<<G * BPG, HBT, 0, stream>>>(src, out_deg, E, N);
        norm_kernel<<<(N + 255) / 256, 256, 0, stream>>>(out_deg, (float*)out_deg, N);
        bhist_kernel<<<256, 256, 0, stream>>>(dst, cntB, E);
        bucket_alloc2<<<(NB + 255) / 256, 256, 0, stream>>>(cntB, gcur, bases, counter, NB);
        bin_kernel<<<(E + RND - 1) / RND, BINT, 0, stream>>>(src, dst, gcur, gbuf, E);
        sort_gather<<<NB, GT, 0, stream>>>(x, (const float*)out_deg, gbuf, bases,
                                           cntB, out, N);
        return;
    }

    // ---- R3 fallback ----
    size_t need3 = ((size_t)3 * N + 1 + (size_t)E) * sizeof(int);
    int* out_deg = (int*)d_ws;
    int* in_deg  = out_deg + N;
    if (ws_size >= need3) {
        int* counter  = in_deg + N;
        int* cursor   = counter + 1;
        int* edge_src = cursor + N;
        hipMemsetAsync(d_ws, 0, ((size_t)2 * N + 1) * sizeof(int), stream);
        deg_kernel<<<(E + 255) / 256, 256, 0, stream>>>(src, dst, out_deg, in_deg, E);
        norm_kernel<<<(N + 255) / 256, 256, 0, stream>>>(out_deg, (float*)out_deg, N);
        alloc_kernel<<<(N + 255) / 256, 256, 0, stream>>>(in_deg, cursor, counter, N);
        fill_kernel<<<(E + 255) / 256, 256, 0, stream>>>(src, dst, cursor, edge_src, E);
        gather_kernel<<<(N * 8 + 255) / 256, 256, 0, stream>>>(
            x, edge_src, cursor, in_deg, (const float*)out_deg, out, N);
    }
}

// Round 9
// 105.928 us; speedup vs baseline: 12.1312x; 1.2596x over previous
//
#include <hip/hip_runtime.h>

#define F 32

// ---- bucket params ----
#define TSB 128        // nodes per bucket
#define TSB_SH 7
#define NBMAX 1024     // bucket arrays padded to this (NB = ceil(N/128) <= 1024)
#define RND 4096       // edges per bin round (one block each)
#define BINT 256       // bin_kernel threads
#define GT 1024        // sort_gather threads: 128 groups x 8 lanes
#define TEDGE 2048     // entries per in-block sort tile

// ---- per-node src hist params (R9: retiled for occupancy) ----
#define SPAN 8192      // nodes per histogram range (32KB LDS)
#define HBT 1024       // 16 waves/block
#define BPG 20         // blocks per range -> grid ~= 260 ~= 1/CU

// LDS histogram of src into out_deg (per node), coalesced flush.
__global__ __launch_bounds__(HBT) void hist_kernel(const int* __restrict__ keys,
                                                   int* __restrict__ deg,
                                                   int E, int N) {
    __shared__ int hist[SPAN];
    int grp = blockIdx.x / BPG;
    int q   = blockIdx.x % BPG;
    int lo  = grp * SPAN;
    int sp  = min(SPAN, N - lo);
    if (sp <= 0) return;
    for (int j = threadIdx.x; j < SPAN; j += HBT) hist[j] = 0;
    __syncthreads();
    int nvec = E >> 2;
    const int4* s4 = (const int4*)keys;
    for (int i = q * HBT + threadIdx.x; i < nvec; i += BPG * HBT) {
        int4 v = s4[i];
        unsigned a;
        a = (unsigned)(v.x - lo); if (a < (unsigned)sp) atomicAdd(&hist[a], 1);
        a = (unsigned)(v.y - lo); if (a < (unsigned)sp) atomicAdd(&hist[a], 1);
        a = (unsigned)(v.z - lo); if (a < (unsigned)sp) atomicAdd(&hist[a], 1);
        a = (unsigned)(v.w - lo); if (a < (unsigned)sp) atomicAdd(&hist[a], 1);
    }
    if (q == 0) {
        int idx = (nvec << 2) + threadIdx.x;
        if (idx < E) {
            unsigned a = (unsigned)(keys[idx] - lo);
            if (a < (unsigned)sp) atomicAdd(&hist[a], 1);
        }
    }
    __syncthreads();
    for (int j = threadIdx.x; j < sp; j += HBT) {
        int v = hist[j];
        if (v) atomicAdd(&deg[lo + j], v);
    }
}

// deg -> rsqrt(max(deg,1)) in place.
__global__ void norm_kernel(const int* __restrict__ deg, float* __restrict__ norm, int n) {
    int i = blockIdx.x * blockDim.x + threadIdx.x;
    if (i < n) {
        int d = deg[i];
        norm[i] = rsqrtf((float)(d > 1 ? d : 1));
    }
}

// Bucket-level histogram: cntB[dst>>7]. One pass over dst, 1024-bin LDS.
__global__ __launch_bounds__(256) void bhist_kernel(const int* __restrict__ dst,
                                                    int* __restrict__ cntB, int E) {
    __shared__ int hist[NBMAX];
    int t = threadIdx.x;
    for (int j = t; j < NBMAX; j += 256) hist[j] = 0;
    __syncthreads();
    int nvec = E >> 2;
    const int4* d4 = (const int4*)dst;
    for (int i = blockIdx.x * 256 + t; i < nvec; i += gridDim.x * 256) {
        int4 v = d4[i];
        atomicAdd(&hist[v.x >> TSB_SH], 1);
        atomicAdd(&hist[v.y >> TSB_SH], 1);
        atomicAdd(&hist[v.z >> TSB_SH], 1);
        atomicAdd(&hist[v.w >> TSB_SH], 1);
    }
    if (blockIdx.x == 0) {
        int idx = (nvec << 2) + t;
        if (idx < E) atomicAdd(&hist[dst[idx] >> TSB_SH], 1);
    }
    __syncthreads();
    for (int j = t; j < NBMAX; j += 256) {
        int v = hist[j];
        if (v) atomicAdd(&cntB[j], v);
    }
}

// Disjoint region per bucket: bases[b]=gcur[b]=atomicAdd(counter,cntB[b]).
__global__ void bucket_alloc2(const int* __restrict__ cntB, int* __restrict__ gcur,
                              int* __restrict__ bases, int* __restrict__ counter, int NB) {
    int b = blockIdx.x * blockDim.x + threadIdx.x;
    if (b < NB) {
        int base = atomicAdd(counter, cntB[b]);
        bases[b] = base;
        gcur[b]  = base;
    }
}

// Bin 4096 edges/block into buckets: LDS count -> scan -> staged compaction ->
// one global atomic per (block,bucket) -> coalesced copy-out of packed entries.
__global__ __launch_bounds__(BINT) void bin_kernel(const int* __restrict__ src,
                                                   const int* __restrict__ dst,
                                                   int* __restrict__ gcur,
                                                   unsigned* __restrict__ gbuf, int E) {
    __shared__ int cnt[NBMAX];
    __shared__ int off2[NBMAX];
    __shared__ int aux[BINT];
    __shared__ int stag_d[RND];
    __shared__ int stag_s[RND];
    int t = threadIdx.x;
    int base = blockIdx.x * RND;
    int tot = min(RND, E - base);
    if (tot <= 0) return;
    for (int j = t; j < NBMAX; j += BINT) cnt[j] = 0;
    __syncthreads();
    for (int j = t; j < tot; j += BINT)
        atomicAdd(&cnt[dst[base + j] >> TSB_SH], 1);
    __syncthreads();
    int c0 = cnt[4*t], c1 = cnt[4*t+1], c2 = cnt[4*t+2], c3 = cnt[4*t+3];
    aux[t] = c0 + c1 + c2 + c3;
    __syncthreads();
    for (int o = 1; o < BINT; o <<= 1) {
        int v = (t >= o) ? aux[t - o] : 0;
        __syncthreads();
        aux[t] += v;
        __syncthreads();
    }
    int eb = t ? aux[t - 1] : 0;
    cnt[4*t]   = eb;                off2[4*t]   = eb;
    cnt[4*t+1] = eb + c0;           off2[4*t+1] = eb + c0;
    cnt[4*t+2] = eb + c0 + c1;      off2[4*t+2] = eb + c0 + c1;
    cnt[4*t+3] = eb + c0 + c1 + c2; off2[4*t+3] = eb + c0 + c1 + c2;
    __syncthreads();
    for (int j = t; j < tot; j += BINT) {
        int d = dst[base + j];
        int s = src[base + j];
        int pos = atomicAdd(&cnt[d >> TSB_SH], 1);
        stag_d[pos] = d;
        stag_s[pos] = s;
    }
    __syncthreads();
    for (int b = t; b < NBMAX; b += BINT) {
        int c = cnt[b] - off2[b];
        if (c > 0) {
            int g = atomicAdd(&gcur[b], c);
            off2[b] = g - off2[b];
        }
    }
    __syncthreads();
    for (int i = t; i < tot; i += BINT) {
        int d = stag_d[i];
        unsigned entry = ((unsigned)(d & (TSB - 1)) << 17) | (unsigned)stag_s[i];
        gbuf[off2[d >> TSB_SH] + i] = entry;
    }
}

// Phase 2: per-bucket counting sort (int LDS atomics only) -> per-node REGISTER
// accumulation. Group g (8 lanes) owns node lo+g; walks its sorted segment,
// accumulating float4 in registers. No LDS float atomics. out written once.
__global__ __launch_bounds__(GT) void sort_gather(const float* __restrict__ x,
                                                  const float* __restrict__ onorm,
                                                  const unsigned* __restrict__ gbuf,
                                                  const int* __restrict__ bases,
                                                  const int* __restrict__ cntB,
                                                  float* __restrict__ out, int N) {
    __shared__ unsigned sbuf[TEDGE];  // sorted entries (8KB)
    __shared__ int cnt[TSB];          // count -> cursor
    __shared__ int seg[TSB];          // segment base
    __shared__ int sb[TSB];           // scan buffer
    __shared__ int indeg[TSB];        // in-degree accumulated over tiles
    int t = threadIdx.x;
    int b = blockIdx.x;
    int lo = b << TSB_SH;
    int sp = min(TSB, N - lo);
    int start = bases[b];
    int total = cntB[b];
    int g = t >> 3;     // 0..127 local node
    int l = t & 7;      // feature quad

    float4 acc = make_float4(0.f, 0.f, 0.f, 0.f);
    if (t < TSB) indeg[t] = 0;
    __syncthreads();

    for (int tile = 0; tile < total; tile += TEDGE) {
        int n = min(TEDGE, total - tile);
        if (t < TSB) cnt[t] = 0;
        __syncthreads();
        // count
        for (int j = t; j < n; j += GT)
            atomicAdd(&cnt[gbuf[start + tile + j] >> 17], 1);
        __syncthreads();
        int c_t = (t < TSB) ? cnt[t] : 0;
        if (t < TSB) sb[t] = c_t;
        __syncthreads();
        // inclusive Hillis-Steele scan over sb[0..127]
        for (int o = 1; o < TSB; o <<= 1) {
            int v = (t < TSB && t >= o) ? sb[t - o] : 0;
            __syncthreads();
            if (t < TSB) sb[t] += v;
            __syncthreads();
        }
        if (t < TSB) {
            int excl = sb[t] - c_t;
            seg[t] = excl;
            cnt[t] = excl;      // live cursor
            indeg[t] += c_t;
        }
        __syncthreads();
        // place (sort by dl)
        for (int j = t; j < n; j += GT) {
            unsigned e = gbuf[start + tile + j];
            int pos = atomicAdd(&cnt[e >> 17], 1);
            sbuf[pos] = e;
        }
        __syncthreads();
        // consume: group g's segment, register accumulation, unroll-2
        {
            int i = seg[g];
            int send = cnt[g];   // == seg[g] + count_g
            for (; i + 1 < send; i += 2) {
                unsigned e0 = sbuf[i], e1 = sbuf[i + 1];
                unsigned s0 = e0 & 0x1FFFFu, s1 = e1 & 0x1FFFFu;
                float c0 = onorm[s0];
                float c1 = onorm[s1];
                float4 v0 = *(const float4*)&x[(size_t)s0 * F + l * 4];
                float4 v1 = *(const float4*)&x[(size_t)s1 * F + l * 4];
                acc.x += v0.x * c0 + v1.x * c1;
                acc.y += v0.y * c0 + v1.y * c1;
                acc.z += v0.z * c0 + v1.z * c1;
                acc.w += v0.w * c0 + v1.w * c1;
            }
            if (i < send) {
                unsigned e0 = sbuf[i];
                unsigned s0 = e0 & 0x1FFFFu;
                float c0 = onorm[s0];
                float4 v0 = *(const float4*)&x[(size_t)s0 * F + l * 4];
                acc.x += v0.x * c0; acc.y += v0.y * c0;
                acc.z += v0.z * c0; acc.w += v0.w * c0;
            }
        }
        __syncthreads();  // protect cnt/sbuf before next tile
    }

    if (g < sp) {
        int dg = indeg[g];
        float inn = rsqrtf((float)(dg > 1 ? dg : 1));
        acc.x *= inn; acc.y *= inn; acc.z *= inn; acc.w *= inn;
        *reinterpret_cast<float4*>(&out[(size_t)(lo + g) * F + l * 4]) = acc;
    }
}

// ================= R3 fallback path =================

__global__ void deg_kernel(const int* __restrict__ src, const int* __restrict__ dst,
                           int* __restrict__ out_deg, int* __restrict__ in_deg, int E) {
    int i = blockIdx.x * blockDim.x + threadIdx.x;
    if (i < E) {
        atomicAdd(&out_deg[src[i]], 1);
        atomicAdd(&in_deg[dst[i]], 1);
    }
}

__global__ void alloc_kernel(const int* __restrict__ in_deg, int* __restrict__ cursor,
                             int* __restrict__ counter, int N) {
    int i = blockIdx.x * blockDim.x + threadIdx.x;
    if (i < N) cursor[i] = atomicAdd(counter, in_deg[i]);
}

__global__ void fill_kernel(const int* __restrict__ src, const int* __restrict__ dst,
                            int* __restrict__ cursor, int* __restrict__ edge_src, int E) {
    int i = blockIdx.x * blockDim.x + threadIdx.x;
    if (i < E) {
        int d = dst[i];
        int slot = atomicAdd(&cursor[d], 1);
        edge_src[slot] = src[i];
    }
}

__global__ void gather_kernel(const float* __restrict__ x,
                              const int* __restrict__ edge_src,
                              const int* __restrict__ cursor_end,
                              const int* __restrict__ in_deg,
                              const float* __restrict__ out_norm,
                              float* __restrict__ out, int N) {
    int t = blockIdx.x * blockDim.x + threadIdx.x;
    int g = t >> 3, l = t & 7;
    if (g >= N) return;
    int deg = in_deg[g];
    int end = cursor_end[g];
    int beg = end - deg;
    float4 acc = make_float4(0.f, 0.f, 0.f, 0.f);
    for (int j = beg; j < end; ++j) {
        int s = edge_src[j];
        float c = out_norm[s];
        float4 v = *reinterpret_cast<const float4*>(&x[s * F + l * 4]);
        acc.x += v.x * c; acc.y += v.y * c; acc.z += v.z * c; acc.w += v.w * c;
    }
    float innorm = rsqrtf((float)(deg > 1 ? deg : 1));
    acc.x *= innorm; acc.y *= innorm; acc.z *= innorm; acc.w *= innorm;
    *reinterpret_cast<float4*>(&out[g * F + l * 4]) = acc;
}

extern "C" void kernel_launch(void* const* d_in, const int* in_sizes, int n_in,
                              void* d_out, int out_size, void* d_ws, size_t ws_size,
                              hipStream_t stream) {
    const float* x  = (const float*)d_in[0];
    const int* src  = (const int*)d_in[1];
    const int* dst  = (const int*)d_in[2];
    float* out      = (float*)d_out;

    const int N = in_sizes[0] / F;   // 100000
    const int E = in_sizes[1];       // 1600000
    const int NB = (N + TSB - 1) / TSB;

    // primary ws layout (4B units):
    // out_deg[N] | counter[8] | cntB[NBMAX] | gcur[NBMAX] | bases[NBMAX] | gbuf[E]
    size_t need = ((size_t)N + 8 + 3 * NBMAX + (size_t)E) * 4;

    if (ws_size >= need && N <= (1 << 17) && NB <= NBMAX) {
        int* out_deg  = (int*)d_ws;
        int* counter  = out_deg + N;
        int* cntB     = counter + 8;
        int* gcur     = cntB + NBMAX;
        int* bases    = gcur + NBMAX;
        unsigned* gbuf = (unsigned*)(bases + NBMAX);

        // zero out_deg, counter, cntB (contiguous head)
        hipMemsetAsync(d_ws, 0, ((size_t)N + 8 + NBMAX) * sizeof(int), stream);

        int G = (N + SPAN - 1) / SPAN;
        hist_kernel<<<G * BPG, HBT, 0, stream>>>(src, out_deg, E, N);
        norm_kernel<<<(N + 255) / 256, 256, 0, stream>>>(out_deg, (float*)out_deg, N);
        bhist_kernel<<<256, 256, 0, stream>>>(dst, cntB, E);
        bucket_alloc2<<<(NB + 255) / 256, 256, 0, stream>>>(cntB, gcur, bases, counter, NB);
        bin_kernel<<<(E + RND - 1) / RND, BINT, 0, stream>>>(src, dst, gcur, gbuf, E);
        sort_gather<<<NB, GT, 0, stream>>>(x, (const float*)out_deg, gbuf, bases,
                                           cntB, out, N);
        return;
    }

    // ---- R3 fallback ----
    size_t need3 = ((size_t)3 * N + 1 + (size_t)E) * sizeof(int);
    int* out_deg = (int*)d_ws;
    int* in_deg  = out_deg + N;
    if (ws_size >= need3) {
        int* counter  = in_deg + N;
        int* cursor   = counter + 1;
        int* edge_src = cursor + N;
        hipMemsetAsync(d_ws, 0, ((size_t)2 * N + 1) * sizeof(int), stream);
        deg_kernel<<<(E + 255) / 256, 256, 0, stream>>>(src, dst, out_deg, in_deg, E);
        norm_kernel<<<(N + 255) / 256, 256, 0, stream>>>(out_deg, (float*)out_deg, N);
        alloc_kernel<<<(N + 255) / 256, 256, 0, stream>>>(in_deg, cursor, counter, N);
        fill_kernel<<<(E + 255) / 256, 256, 0, stream>>>(src, dst, cursor, edge_src, E);
        gather_kernel<<<(N * 8 + 255) / 256, 256, 0, stream>>>(
            x, edge_src, cursor, in_deg, (const float*)out_deg, out, N);
    }
}

// Round 10
// 103.729 us; speedup vs baseline: 12.3884x; 1.0212x over previous
//
#include <hip/hip_runtime.h>

#define F 32

// ---- bucket params ----
#define TSB 128        // nodes per bucket
#define TSB_SH 7
#define NBMAX 1024     // bucket arrays padded to this (NB = ceil(N/128) <= 1024)
#define RND 4096       // edges per bin round (one block each)
#define BINT 256       // bin_kernel threads
#define GT 1024        // sort_gather threads: 128 groups x 8 lanes
#define TEDGE 2048     // entries per in-block sort tile

// ---- per-node src hist params ----
#define SPAN 8192      // nodes per histogram range (32KB LDS)
#define HBT 1024       // 16 waves/block
#define BPG 20         // blocks per range -> grid ~= 260 ~= 1/CU

// Zero the scratch head (out_deg[N] | counter[8] | cntB[NBMAX]) with a real
// grid. The runtime's fillBufferAligned was taking ~40us/replay under graph
// capture (tiny grid); this does 404KB in ~1-2us.
__global__ void zero_kernel(int4* __restrict__ p, int n4) {
    int i = blockIdx.x * blockDim.x + threadIdx.x;
    int stride = gridDim.x * blockDim.x;
    for (; i < n4; i += stride) p[i] = make_int4(0, 0, 0, 0);
}

// LDS histogram of src into out_deg (per node), coalesced flush.
__global__ __launch_bounds__(HBT) void hist_kernel(const int* __restrict__ keys,
                                                   int* __restrict__ deg,
                                                   int E, int N) {
    __shared__ int hist[SPAN];
    int grp = blockIdx.x / BPG;
    int q   = blockIdx.x % BPG;
    int lo  = grp * SPAN;
    int sp  = min(SPAN, N - lo);
    if (sp <= 0) return;
    for (int j = threadIdx.x; j < SPAN; j += HBT) hist[j] = 0;
    __syncthreads();
    int nvec = E >> 2;
    const int4* s4 = (const int4*)keys;
    for (int i = q * HBT + threadIdx.x; i < nvec; i += BPG * HBT) {
        int4 v = s4[i];
        unsigned a;
        a = (unsigned)(v.x - lo); if (a < (unsigned)sp) atomicAdd(&hist[a], 1);
        a = (unsigned)(v.y - lo); if (a < (unsigned)sp) atomicAdd(&hist[a], 1);
        a = (unsigned)(v.z - lo); if (a < (unsigned)sp) atomicAdd(&hist[a], 1);
        a = (unsigned)(v.w - lo); if (a < (unsigned)sp) atomicAdd(&hist[a], 1);
    }
    if (q == 0) {
        int idx = (nvec << 2) + threadIdx.x;
        if (idx < E) {
            unsigned a = (unsigned)(keys[idx] - lo);
            if (a < (unsigned)sp) atomicAdd(&hist[a], 1);
        }
    }
    __syncthreads();
    for (int j = threadIdx.x; j < sp; j += HBT) {
        int v = hist[j];
        if (v) atomicAdd(&deg[lo + j], v);
    }
}

// Bucket-level histogram: cntB[dst>>7]. One pass over dst, 1024-bin LDS.
__global__ __launch_bounds__(256) void bhist_kernel(const int* __restrict__ dst,
                                                    int* __restrict__ cntB, int E) {
    __shared__ int hist[NBMAX];
    int t = threadIdx.x;
    for (int j = t; j < NBMAX; j += 256) hist[j] = 0;
    __syncthreads();
    int nvec = E >> 2;
    const int4* d4 = (const int4*)dst;
    for (int i = blockIdx.x * 256 + t; i < nvec; i += gridDim.x * 256) {
        int4 v = d4[i];
        atomicAdd(&hist[v.x >> TSB_SH], 1);
        atomicAdd(&hist[v.y >> TSB_SH], 1);
        atomicAdd(&hist[v.z >> TSB_SH], 1);
        atomicAdd(&hist[v.w >> TSB_SH], 1);
    }
    if (blockIdx.x == 0) {
        int idx = (nvec << 2) + t;
        if (idx < E) atomicAdd(&hist[dst[idx] >> TSB_SH], 1);
    }
    __syncthreads();
    for (int j = t; j < NBMAX; j += 256) {
        int v = hist[j];
        if (v) atomicAdd(&cntB[j], v);
    }
}

// Fused: norm (out_deg -> rsqrt, in place) + per-bucket region alloc.
__global__ void norm_alloc_kernel(int* __restrict__ deg_norm,
                                  const int* __restrict__ cntB,
                                  int* __restrict__ gcur, int* __restrict__ bases,
                                  int* __restrict__ counter, int N, int NB) {
    int i = blockIdx.x * blockDim.x + threadIdx.x;
    if (i < N) {
        int d = deg_norm[i];
        ((float*)deg_norm)[i] = rsqrtf((float)(d > 1 ? d : 1));
    }
    if (i < NB) {
        int base = atomicAdd(counter, cntB[i]);
        bases[i] = base;
        gcur[i]  = base;
    }
}

// Bin 4096 edges/block into buckets: LDS count -> scan -> staged compaction ->
// one global atomic per (block,bucket) -> coalesced copy-out of packed entries.
__global__ __launch_bounds__(BINT) void bin_kernel(const int* __restrict__ src,
                                                   const int* __restrict__ dst,
                                                   int* __restrict__ gcur,
                                                   unsigned* __restrict__ gbuf, int E) {
    __shared__ int cnt[NBMAX];
    __shared__ int off2[NBMAX];
    __shared__ int aux[BINT];
    __shared__ int stag_d[RND];
    __shared__ int stag_s[RND];
    int t = threadIdx.x;
    int base = blockIdx.x * RND;
    int tot = min(RND, E - base);
    if (tot <= 0) return;
    for (int j = t; j < NBMAX; j += BINT) cnt[j] = 0;
    __syncthreads();
    for (int j = t; j < tot; j += BINT)
        atomicAdd(&cnt[dst[base + j] >> TSB_SH], 1);
    __syncthreads();
    int c0 = cnt[4*t], c1 = cnt[4*t+1], c2 = cnt[4*t+2], c3 = cnt[4*t+3];
    aux[t] = c0 + c1 + c2 + c3;
    __syncthreads();
    for (int o = 1; o < BINT; o <<= 1) {
        int v = (t >= o) ? aux[t - o] : 0;
        __syncthreads();
        aux[t] += v;
        __syncthreads();
    }
    int eb = t ? aux[t - 1] : 0;
    cnt[4*t]   = eb;                off2[4*t]   = eb;
    cnt[4*t+1] = eb + c0;           off2[4*t+1] = eb + c0;
    cnt[4*t+2] = eb + c0 + c1;      off2[4*t+2] = eb + c0 + c1;
    cnt[4*t+3] = eb + c0 + c1 + c2; off2[4*t+3] = eb + c0 + c1 + c2;
    __syncthreads();
    for (int j = t; j < tot; j += BINT) {
        int d = dst[base + j];
        int s = src[base + j];
        int pos = atomicAdd(&cnt[d >> TSB_SH], 1);
        stag_d[pos] = d;
        stag_s[pos] = s;
    }
    __syncthreads();
    for (int b = t; b < NBMAX; b += BINT) {
        int c = cnt[b] - off2[b];
        if (c > 0) {
            int g = atomicAdd(&gcur[b], c);
            off2[b] = g - off2[b];
        }
    }
    __syncthreads();
    for (int i = t; i < tot; i += BINT) {
        int d = stag_d[i];
        unsigned entry = ((unsigned)(d & (TSB - 1)) << 17) | (unsigned)stag_s[i];
        gbuf[off2[d >> TSB_SH] + i] = entry;
    }
}

// Phase 2: per-bucket counting sort (int LDS atomics only) -> per-node REGISTER
// accumulation. Group g (8 lanes) owns node lo+g; walks its sorted segment.
__global__ __launch_bounds__(GT) void sort_gather(const float* __restrict__ x,
                                                  const float* __restrict__ onorm,
                                                  const unsigned* __restrict__ gbuf,
                                                  const int* __restrict__ bases,
                                                  const int* __restrict__ cntB,
                                                  float* __restrict__ out, int N) {
    __shared__ unsigned sbuf[TEDGE];  // sorted entries (8KB)
    __shared__ int cnt[TSB];          // count -> cursor
    __shared__ int seg[TSB];          // segment base
    __shared__ int sb[TSB];           // scan buffer
    __shared__ int indeg[TSB];        // in-degree accumulated over tiles
    int t = threadIdx.x;
    int b = blockIdx.x;
    int lo = b << TSB_SH;
    int sp = min(TSB, N - lo);
    int start = bases[b];
    int total = cntB[b];
    int g = t >> 3;     // 0..127 local node
    int l = t & 7;      // feature quad

    float4 acc = make_float4(0.f, 0.f, 0.f, 0.f);
    if (t < TSB) indeg[t] = 0;
    __syncthreads();

    for (int tile = 0; tile < total; tile += TEDGE) {
        int n = min(TEDGE, total - tile);
        if (t < TSB) cnt[t] = 0;
        __syncthreads();
        for (int j = t; j < n; j += GT)
            atomicAdd(&cnt[gbuf[start + tile + j] >> 17], 1);
        __syncthreads();
        int c_t = (t < TSB) ? cnt[t] : 0;
        if (t < TSB) sb[t] = c_t;
        __syncthreads();
        for (int o = 1; o < TSB; o <<= 1) {
            int v = (t < TSB && t >= o) ? sb[t - o] : 0;
            __syncthreads();
            if (t < TSB) sb[t] += v;
            __syncthreads();
        }
        if (t < TSB) {
            int excl = sb[t] - c_t;
            seg[t] = excl;
            cnt[t] = excl;      // live cursor
            indeg[t] += c_t;
        }
        __syncthreads();
        for (int j = t; j < n; j += GT) {
            unsigned e = gbuf[start + tile + j];
            int pos = atomicAdd(&cnt[e >> 17], 1);
            sbuf[pos] = e;
        }
        __syncthreads();
        {
            int i = seg[g];
            int send = cnt[g];
            for (; i + 1 < send; i += 2) {
                unsigned e0 = sbuf[i], e1 = sbuf[i + 1];
                unsigned s0 = e0 & 0x1FFFFu, s1 = e1 & 0x1FFFFu;
                float c0 = onorm[s0];
                float c1 = onorm[s1];
                float4 v0 = *(const float4*)&x[(size_t)s0 * F + l * 4];
                float4 v1 = *(const float4*)&x[(size_t)s1 * F + l * 4];
                acc.x += v0.x * c0 + v1.x * c1;
                acc.y += v0.y * c0 + v1.y * c1;
                acc.z += v0.z * c0 + v1.z * c1;
                acc.w += v0.w * c0 + v1.w * c1;
            }
            if (i < send) {
                unsigned e0 = sbuf[i];
                unsigned s0 = e0 & 0x1FFFFu;
                float c0 = onorm[s0];
                float4 v0 = *(const float4*)&x[(size_t)s0 * F + l * 4];
                acc.x += v0.x * c0; acc.y += v0.y * c0;
                acc.z += v0.z * c0; acc.w += v0.w * c0;
            }
        }
        __syncthreads();
    }

    if (g < sp) {
        int dg = indeg[g];
        float inn = rsqrtf((float)(dg > 1 ? dg : 1));
        acc.x *= inn; acc.y *= inn; acc.z *= inn; acc.w *= inn;
        *reinterpret_cast<float4*>(&out[(size_t)(lo + g) * F + l * 4]) = acc;
    }
}

// ================= R3 fallback path =================

__global__ void deg_kernel(const int* __restrict__ src, const int* __restrict__ dst,
                           int* __restrict__ out_deg, int* __restrict__ in_deg, int E) {
    int i = blockIdx.x * blockDim.x + threadIdx.x;
    if (i < E) {
        atomicAdd(&out_deg[src[i]], 1);
        atomicAdd(&in_deg[dst[i]], 1);
    }
}

__global__ void norm_kernel(const int* __restrict__ deg, float* __restrict__ norm, int n) {
    int i = blockIdx.x * blockDim.x + threadIdx.x;
    if (i < n) {
        int d = deg[i];
        norm[i] = rsqrtf((float)(d > 1 ? d : 1));
    }
}

__global__ void alloc_kernel(const int* __restrict__ in_deg, int* __restrict__ cursor,
                             int* __restrict__ counter, int N) {
    int i = blockIdx.x * blockDim.x + threadIdx.x;
    if (i < N) cursor[i] = atomicAdd(counter, in_deg[i]);
}

__global__ void fill_kernel(const int* __restrict__ src, const int* __restrict__ dst,
                            int* __restrict__ cursor, int* __restrict__ edge_src, int E) {
    int i = blockIdx.x * blockDim.x + threadIdx.x;
    if (i < E) {
        int d = dst[i];
        int slot = atomicAdd(&cursor[d], 1);
        edge_src[slot] = src[i];
    }
}

__global__ void gather_kernel(const float* __restrict__ x,
                              const int* __restrict__ edge_src,
                              const int* __restrict__ cursor_end,
                              const int* __restrict__ in_deg,
                              const float* __restrict__ out_norm,
                              float* __restrict__ out, int N) {
    int t = blockIdx.x * blockDim.x + threadIdx.x;
    int g = t >> 3, l = t & 7;
    if (g >= N) return;
    int deg = in_deg[g];
    int end = cursor_end[g];
    int beg = end - deg;
    float4 acc = make_float4(0.f, 0.f, 0.f, 0.f);
    for (int j = beg; j < end; ++j) {
        int s = edge_src[j];
        float c = out_norm[s];
        float4 v = *reinterpret_cast<const float4*>(&x[s * F + l * 4]);
        acc.x += v.x * c; acc.y += v.y * c; acc.z += v.z * c; acc.w += v.w * c;
    }
    float innorm = rsqrtf((float)(deg > 1 ? deg : 1));
    acc.x *= innorm; acc.y *= innorm; acc.z *= innorm; acc.w *= innorm;
    *reinterpret_cast<float4*>(&out[g * F + l * 4]) = acc;
}

extern "C" void kernel_launch(void* const* d_in, const int* in_sizes, int n_in,
                              void* d_out, int out_size, void* d_ws, size_t ws_size,
                              hipStream_t stream) {
    const float* x  = (const float*)d_in[0];
    const int* src  = (const int*)d_in[1];
    const int* dst  = (const int*)d_in[2];
    float* out      = (float*)d_out;

    const int N = in_sizes[0] / F;   // 100000
    const int E = in_sizes[1];       // 1600000
    const int NB = (N + TSB - 1) / TSB;

    // primary ws layout (4B units):
    // out_deg[N] | counter[8] | cntB[NBMAX] | gcur[NBMAX] | bases[NBMAX] | gbuf[E]
    size_t need = ((size_t)N + 8 + 3 * NBMAX + (size_t)E) * 4;

    if (ws_size >= need && N <= (1 << 17) && NB <= NBMAX) {
        int* out_deg  = (int*)d_ws;
        int* counter  = out_deg + N;
        int* cntB     = counter + 8;
        int* gcur     = cntB + NBMAX;
        int* bases    = gcur + NBMAX;
        unsigned* gbuf = (unsigned*)(bases + NBMAX);

        // zero out_deg | counter | cntB head with a real grid (NOT hipMemsetAsync:
        // the runtime fill kernel cost ~40us/replay under graph capture)
        int zn4 = (int)(((size_t)N + 8 + NBMAX) / 4);  // head is 16B-divisible when N%4==0
        zero_kernel<<<128, 256, 0, stream>>>((int4*)d_ws, zn4);

        int G = (N + SPAN - 1) / SPAN;
        hist_kernel<<<G * BPG, HBT, 0, stream>>>(src, out_deg, E, N);
        bhist_kernel<<<256, 256, 0, stream>>>(dst, cntB, E);
        norm_alloc_kernel<<<(N + 255) / 256, 256, 0, stream>>>(
            out_deg, cntB, gcur, bases, counter, N, NB);
        bin_kernel<<<(E + RND - 1) / RND, BINT, 0, stream>>>(src, dst, gcur, gbuf, E);
        sort_gather<<<NB, GT, 0, stream>>>(x, (const float*)out_deg, gbuf, bases,
                                           cntB, out, N);
        return;
    }

    // ---- R3 fallback ----
    size_t need3 = ((size_t)3 * N + 1 + (size_t)E) * sizeof(int);
    int* out_deg = (int*)d_ws;
    int* in_deg  = out_deg + N;
    if (ws_size >= need3) {
        int* counter  = in_deg + N;
        int* cursor   = counter + 1;
        int* edge_src = cursor + N;
        hipMemsetAsync(d_ws, 0, ((size_t)2 * N + 1) * sizeof(int), stream);
        deg_kernel<<<(E + 255) / 256, 256, 0, stream>>>(src, dst, out_deg, in_deg, E);
        norm_kernel<<<(N + 255) / 256, 256, 0, stream>>>(out_deg, (float*)out_deg, N);
        alloc_kernel<<<(N + 255) / 256, 256, 0, stream>>>(in_deg, cursor, counter, N);
        fill_kernel<<<(E + 255) / 256, 256, 0, stream>>>(src, dst, cursor, edge_src, E);
        gather_kernel<<<(N * 8 + 255) / 256, 256, 0, stream>>>(
            x, edge_src, cursor, in_deg, (const float*)out_deg, out, N);
    }
}

// Round 11
// 94.832 us; speedup vs baseline: 13.5506x; 1.0938x over previous
//
#include <hip/hip_runtime.h>

#define F 32

// ---- bucket params ----
#define TSB 128        // nodes per bucket
#define TSB_SH 7
#define NBMAX 1024     // bucket arrays padded to this (NB = ceil(N/128) <= 1024)
#define RND 4096       // edges per bin round (one block each)
#define BINT 256       // bin_kernel threads
#define GT 512         // sort_gather threads: 64 groups x 8 lanes, 2 nodes/group
#define TEDGE 2048     // entries per in-block sort tile

// ---- per-node src hist params ----
#define SPAN 8192      // nodes per histogram range (32KB LDS)
#define HBT 1024       // 16 waves/block
#define BPG 20         // blocks per range -> grid ~= 260 ~= 1/CU

// Zero scratch head with a real grid (runtime fillBufferAligned is slow under
// graph capture).
__global__ void zero_kernel(int4* __restrict__ p, int n4) {
    int i = blockIdx.x * blockDim.x + threadIdx.x;
    int stride = gridDim.x * blockDim.x;
    for (; i < n4; i += stride) p[i] = make_int4(0, 0, 0, 0);
}

// Fused: per-node src histogram (range grp) + per-bucket dst histogram
// (each block does its 1/grid slice of dst into a 1024-bin LDS hist).
__global__ __launch_bounds__(HBT) void hist2_kernel(const int* __restrict__ src,
                                                    const int* __restrict__ dst,
                                                    int* __restrict__ out_deg,
                                                    int* __restrict__ cntB,
                                                    int E, int N) {
    __shared__ int hist[SPAN];   // 32KB: per-node src counts for range grp
    __shared__ int bh[NBMAX];    // 4KB : per-bucket dst counts (slice)
    int t   = threadIdx.x;
    int grp = blockIdx.x / BPG;
    int q   = blockIdx.x % BPG;
    int lo  = grp * SPAN;
    int sp  = min(SPAN, N - lo);
    bool have_range = (sp > 0);   // block-uniform

    if (have_range)
        for (int j = t; j < SPAN; j += HBT) hist[j] = 0;
    for (int j = t; j < NBMAX; j += HBT) bh[j] = 0;
    __syncthreads();

    int nvec = E >> 2;
    // part A: dst bucket hist over this block's slice
    const int4* d4 = (const int4*)dst;
    for (int i = blockIdx.x * HBT + t; i < nvec; i += gridDim.x * HBT) {
        int4 v = d4[i];
        atomicAdd(&bh[v.x >> TSB_SH], 1);
        atomicAdd(&bh[v.y >> TSB_SH], 1);
        atomicAdd(&bh[v.z >> TSB_SH], 1);
        atomicAdd(&bh[v.w >> TSB_SH], 1);
    }
    if (blockIdx.x == 0) {
        int idx = (nvec << 2) + t;
        if (idx < E) atomicAdd(&bh[dst[idx] >> TSB_SH], 1);
    }
    // part B: src per-node hist for range grp (stride over full src)
    if (have_range) {
        const int4* s4 = (const int4*)src;
        for (int i = q * HBT + t; i < nvec; i += BPG * HBT) {
            int4 v = s4[i];
            unsigned a;
            a = (unsigned)(v.x - lo); if (a < (unsigned)sp) atomicAdd(&hist[a], 1);
            a = (unsigned)(v.y - lo); if (a < (unsigned)sp) atomicAdd(&hist[a], 1);
            a = (unsigned)(v.z - lo); if (a < (unsigned)sp) atomicAdd(&hist[a], 1);
            a = (unsigned)(v.w - lo); if (a < (unsigned)sp) atomicAdd(&hist[a], 1);
        }
        if (q == 0) {
            int idx = (nvec << 2) + t;
            if (idx < E) {
                unsigned a = (unsigned)(src[idx] - lo);
                if (a < (unsigned)sp) atomicAdd(&hist[a], 1);
            }
        }
    }
    __syncthreads();
    for (int j = t; j < NBMAX; j += HBT) {
        int v = bh[j];
        if (v) atomicAdd(&cntB[j], v);
    }
    if (have_range)
        for (int j = t; j < sp; j += HBT) {
            int v = hist[j];
            if (v) atomicAdd(&out_deg[lo + j], v);
        }
}

// Fused: norm (out_deg -> rsqrt, in place) + per-bucket region alloc.
__global__ void norm_alloc_kernel(int* __restrict__ deg_norm,
                                  const int* __restrict__ cntB,
                                  int* __restrict__ gcur, int* __restrict__ bases,
                                  int* __restrict__ counter, int N, int NB) {
    int i = blockIdx.x * blockDim.x + threadIdx.x;
    if (i < N) {
        int d = deg_norm[i];
        ((float*)deg_norm)[i] = rsqrtf((float)(d > 1 ? d : 1));
    }
    if (i < NB) {
        int base = atomicAdd(counter, cntB[i]);
        bases[i] = base;
        gcur[i]  = base;
    }
}

// Bin 4096 edges/block into buckets (validated R6-R10, unchanged).
__global__ __launch_bounds__(BINT) void bin_kernel(const int* __restrict__ src,
                                                   const int* __restrict__ dst,
                                                   int* __restrict__ gcur,
                                                   unsigned* __restrict__ gbuf, int E) {
    __shared__ int cnt[NBMAX];
    __shared__ int off2[NBMAX];
    __shared__ int aux[BINT];
    __shared__ int stag_d[RND];
    __shared__ int stag_s[RND];
    int t = threadIdx.x;
    int base = blockIdx.x * RND;
    int tot = min(RND, E - base);
    if (tot <= 0) return;
    for (int j = t; j < NBMAX; j += BINT) cnt[j] = 0;
    __syncthreads();
    for (int j = t; j < tot; j += BINT)
        atomicAdd(&cnt[dst[base + j] >> TSB_SH], 1);
    __syncthreads();
    int c0 = cnt[4*t], c1 = cnt[4*t+1], c2 = cnt[4*t+2], c3 = cnt[4*t+3];
    aux[t] = c0 + c1 + c2 + c3;
    __syncthreads();
    for (int o = 1; o < BINT; o <<= 1) {
        int v = (t >= o) ? aux[t - o] : 0;
        __syncthreads();
        aux[t] += v;
        __syncthreads();
    }
    int eb = t ? aux[t - 1] : 0;
    cnt[4*t]   = eb;                off2[4*t]   = eb;
    cnt[4*t+1] = eb + c0;           off2[4*t+1] = eb + c0;
    cnt[4*t+2] = eb + c0 + c1;      off2[4*t+2] = eb + c0 + c1;
    cnt[4*t+3] = eb + c0 + c1 + c2; off2[4*t+3] = eb + c0 + c1 + c2;
    __syncthreads();
    for (int j = t; j < tot; j += BINT) {
        int d = dst[base + j];
        int s = src[base + j];
        int pos = atomicAdd(&cnt[d >> TSB_SH], 1);
        stag_d[pos] = d;
        stag_s[pos] = s;
    }
    __syncthreads();
    for (int b = t; b < NBMAX; b += BINT) {
        int c = cnt[b] - off2[b];
        if (c > 0) {
            int g = atomicAdd(&gcur[b], c);
            off2[b] = g - off2[b];
        }
    }
    __syncthreads();
    for (int i = t; i < tot; i += BINT) {
        int d = stag_d[i];
        unsigned entry = ((unsigned)(d & (TSB - 1)) << 17) | (unsigned)stag_s[i];
        gbuf[off2[d >> TSB_SH] + i] = entry;
    }
}

// Phase 2: counting sort (wave-0 shfl scan, 5 barriers/tile) + register
// accumulation. 512 threads: 64 groups x 8 lanes; group g owns nodes g, g+64.
// 4 blocks/CU -> 32 waves/CU occupancy.
__global__ __launch_bounds__(GT) void sort_gather(const float* __restrict__ x,
                                                  const float* __restrict__ onorm,
                                                  const unsigned* __restrict__ gbuf,
                                                  const int* __restrict__ bases,
                                                  const int* __restrict__ cntB,
                                                  float* __restrict__ out, int N) {
    __shared__ unsigned sbuf[TEDGE];  // 8KB
    __shared__ int cnt[TSB];          // count -> cursor -> segment end
    __shared__ int seg[TSB];          // segment base
    __shared__ int indeg[TSB];
    int t = threadIdx.x;
    int b = blockIdx.x;
    int lo = b << TSB_SH;
    int sp = min(TSB, N - lo);
    int start = bases[b];
    int total = cntB[b];
    int ga = t >> 3;    // 0..63; owns nodes ga and ga+64
    int l  = t & 7;

    float4 acc0 = make_float4(0.f, 0.f, 0.f, 0.f);
    float4 acc1 = make_float4(0.f, 0.f, 0.f, 0.f);
    if (t < TSB) indeg[t] = 0;
    __syncthreads();

    for (int tile = 0; tile < total; tile += TEDGE) {
        int n = min(TEDGE, total - tile);
        if (t < TSB) cnt[t] = 0;
        __syncthreads();
        // count
        for (int j = t; j < n; j += GT)
            atomicAdd(&cnt[gbuf[start + tile + j] >> 17], 1);
        __syncthreads();
        if (t < TSB) indeg[t] += cnt[t];
        __syncthreads();
        // wave-0 scan of cnt[128] (2 bins/lane, shfl inclusive scan)
        if (t < 64) {
            int c0 = cnt[2 * t], c1 = cnt[2 * t + 1];
            int p = c0 + c1;
            #pragma unroll
            for (int o = 1; o < 64; o <<= 1) {
                int v = __shfl_up(p, o, 64);
                if (t >= o) p += v;
            }
            int excl = p - (c0 + c1);
            seg[2 * t] = excl;       cnt[2 * t] = excl;
            seg[2 * t + 1] = excl + c0; cnt[2 * t + 1] = excl + c0;
        }
        __syncthreads();
        // place (sort by local node)
        for (int j = t; j < n; j += GT) {
            unsigned e = gbuf[start + tile + j];
            int pos = atomicAdd(&cnt[e >> 17], 1);
            sbuf[pos] = e;
        }
        __syncthreads();
        // consume both segments with register accumulation
        #pragma unroll
        for (int half = 0; half < 2; ++half) {
            int g = ga + half * 64;
            float4* accp = half ? &acc1 : &acc0;
            int i = seg[g];
            int send = cnt[g];
            float4 a = *accp;
            for (; i + 1 < send; i += 2) {
                unsigned e0 = sbuf[i], e1 = sbuf[i + 1];
                unsigned s0 = e0 & 0x1FFFFu, s1 = e1 & 0x1FFFFu;
                float c0 = onorm[s0];
                float c1 = onorm[s1];
                float4 v0 = *(const float4*)&x[(size_t)s0 * F + l * 4];
                float4 v1 = *(const float4*)&x[(size_t)s1 * F + l * 4];
                a.x += v0.x * c0 + v1.x * c1;
                a.y += v0.y * c0 + v1.y * c1;
                a.z += v0.z * c0 + v1.z * c1;
                a.w += v0.w * c0 + v1.w * c1;
            }
            if (i < send) {
                unsigned e0 = sbuf[i];
                unsigned s0 = e0 & 0x1FFFFu;
                float c0 = onorm[s0];
                float4 v0 = *(const float4*)&x[(size_t)s0 * F + l * 4];
                a.x += v0.x * c0; a.y += v0.y * c0;
                a.z += v0.z * c0; a.w += v0.w * c0;
            }
            *accp = a;
        }
        __syncthreads();  // protect cnt/sbuf before next tile
    }

    #pragma unroll
    for (int half = 0; half < 2; ++half) {
        int g = ga + half * 64;
        if (g < sp) {
            float4 a = half ? acc1 : acc0;
            int dg = indeg[g];
            float inn = rsqrtf((float)(dg > 1 ? dg : 1));
            a.x *= inn; a.y *= inn; a.z *= inn; a.w *= inn;
            *reinterpret_cast<float4*>(&out[(size_t)(lo + g) * F + l * 4]) = a;
        }
    }
}

// ================= R3 fallback path =================

__global__ void deg_kernel(const int* __restrict__ src, const int* __restrict__ dst,
                           int* __restrict__ out_deg, int* __restrict__ in_deg, int E) {
    int i = blockIdx.x * blockDim.x + threadIdx.x;
    if (i < E) {
        atomicAdd(&out_deg[src[i]], 1);
        atomicAdd(&in_deg[dst[i]], 1);
    }
}

__global__ void norm_kernel(const int* __restrict__ deg, float* __restrict__ norm, int n) {
    int i = blockIdx.x * blockDim.x + threadIdx.x;
    if (i < n) {
        int d = deg[i];
        norm[i] = rsqrtf((float)(d > 1 ? d : 1));
    }
}

__global__ void alloc_kernel(const int* __restrict__ in_deg, int* __restrict__ cursor,
                             int* __restrict__ counter, int N) {
    int i = blockIdx.x * blockDim.x + threadIdx.x;
    if (i < N) cursor[i] = atomicAdd(counter, in_deg[i]);
}

__global__ void fill_kernel(const int* __restrict__ src, const int* __restrict__ dst,
                            int* __restrict__ cursor, int* __restrict__ edge_src, int E) {
    int i = blockIdx.x * blockDim.x + threadIdx.x;
    if (i < E) {
        int d = dst[i];
        int slot = atomicAdd(&cursor[d], 1);
        edge_src[slot] = src[i];
    }
}

__global__ void gather_kernel(const float* __restrict__ x,
                              const int* __restrict__ edge_src,
                              const int* __restrict__ cursor_end,
                              const int* __restrict__ in_deg,
                              const float* __restrict__ out_norm,
                              float* __restrict__ out, int N) {
    int t = blockIdx.x * blockDim.x + threadIdx.x;
    int g = t >> 3, l = t & 7;
    if (g >= N) return;
    int deg = in_deg[g];
    int end = cursor_end[g];
    int beg = end - deg;
    float4 acc = make_float4(0.f, 0.f, 0.f, 0.f);
    for (int j = beg; j < end; ++j) {
        int s = edge_src[j];
        float c = out_norm[s];
        float4 v = *reinterpret_cast<const float4*>(&x[s * F + l * 4]);
        acc.x += v.x * c; acc.y += v.y * c; acc.z += v.z * c; acc.w += v.w * c;
    }
    float innorm = rsqrtf((float)(deg > 1 ? deg : 1));
    acc.x *= innorm; acc.y *= innorm; acc.z *= innorm; acc.w *= innorm;
    *reinterpret_cast<float4*>(&out[g * F + l * 4]) = acc;
}

extern "C" void kernel_launch(void* const* d_in, const int* in_sizes, int n_in,
                              void* d_out, int out_size, void* d_ws, size_t ws_size,
                              hipStream_t stream) {
    const float* x  = (const float*)d_in[0];
    const int* src  = (const int*)d_in[1];
    const int* dst  = (const int*)d_in[2];
    float* out      = (float*)d_out;

    const int N = in_sizes[0] / F;   // 100000
    const int E = in_sizes[1];       // 1600000
    const int NB = (N + TSB - 1) / TSB;

    // primary ws layout (4B units):
    // out_deg[N] | counter[8] | cntB[NBMAX] | gcur[NBMAX] | bases[NBMAX] | gbuf[E]
    size_t need = ((size_t)N + 8 + 3 * NBMAX + (size_t)E) * 4;

    if (ws_size >= need && N <= (1 << 17) && NB <= NBMAX) {
        int* out_deg  = (int*)d_ws;
        int* counter  = out_deg + N;
        int* cntB     = counter + 8;
        int* gcur     = cntB + NBMAX;
        int* bases    = gcur + NBMAX;
        unsigned* gbuf = (unsigned*)(bases + NBMAX);

        int zn4 = (int)(((size_t)N + 8 + NBMAX) / 4);
        zero_kernel<<<128, 256, 0, stream>>>((int4*)d_ws, zn4);

        int G = (N + SPAN - 1) / SPAN;
        hist2_kernel<<<G * BPG, HBT, 0, stream>>>(src, dst, out_deg, cntB, E, N);
        norm_alloc_kernel<<<(N + 255) / 256, 256, 0, stream>>>(
            out_deg, cntB, gcur, bases, counter, N, NB);
        bin_kernel<<<(E + RND - 1) / RND, BINT, 0, stream>>>(src, dst, gcur, gbuf, E);
        sort_gather<<<NB, GT, 0, stream>>>(x, (const float*)out_deg, gbuf, bases,
                                           cntB, out, N);
        return;
    }

    // ---- R3 fallback ----
    size_t need3 = ((size_t)3 * N + 1 + (size_t)E) * sizeof(int);
    int* out_deg = (int*)d_ws;
    int* in_deg  = out_deg + N;
    if (ws_size >= need3) {
        int* counter  = in_deg + N;
        int* cursor   = counter + 1;
        int* edge_src = cursor + N;
        hipMemsetAsync(d_ws, 0, ((size_t)2 * N + 1) * sizeof(int), stream);
        deg_kernel<<<(E + 255) / 256, 256, 0, stream>>>(src, dst, out_deg, in_deg, E);
        norm_kernel<<<(N + 255) / 256, 256, 0, stream>>>(out_deg, (float*)out_deg, N);
        alloc_kernel<<<(N + 255) / 256, 256, 0, stream>>>(in_deg, cursor, counter, N);
        fill_kernel<<<(E + 255) / 256, 256, 0, stream>>>(src, dst, cursor, edge_src, E);
        gather_kernel<<<(N * 8 + 255) / 256, 256, 0, stream>>>(
            x, edge_src, cursor, in_deg, (const float*)out_deg, out, N);
    }
}